// Round 18
// baseline (228.505 us; speedup 1.0000x reference)
//
#include <hip/hip_runtime.h>
#include <hip/hip_bf16.h>
#include <cstdint>
#include <cstddef>

#define B_ 2
#define N_ 8192
#define C_ 128
#define K_ 16
#define NK_ (N_ * K_)
#define EPS_ 1e-5f
#define SLOPE_ 0.2f
#define INF_ 3.0e38f

typedef __attribute__((ext_vector_type(8))) short short8;
typedef __attribute__((ext_vector_type(4))) float f32x4;

// ---------------- workspace layout (bytes) ----------------
static constexpr size_t OFF_IDX   = 0x000000;   // int[B*N*16]          1 MB
static constexpr size_t OFF_CPK   = 0x100000;   // float4[B*N]          256 KB
static constexpr size_t OFF_CPK64 = 0x140000;   // double4[B*N]         512 KB
static constexpr size_t OFF_ACC   = 0x1C0000;   // float[2048]          8 KB
static constexpr size_t OFF_WC1   = 0x1D0000;   // bf16[256*128]        64 KB
static constexpr size_t OFF_WC2   = 0x1E0000;   // bf16[512*128]        128 KB
static constexpr size_t OFF_WB3   = 0x200000;   // bf16[128*512]        128 KB
static constexpr size_t OFF_X3T   = 0x240000;                            // bf16[B*N*512] 16 MB
static constexpr size_t OFF_PQ    = OFF_X3T + (size_t)B_ * N_ * 512 * 2; // 32 MB: pq1/pq2 (bf16) -> ht (f32)
// total ~50.25 MB

__device__ __forceinline__ __hip_bfloat16 ftob(float f) { return __float2bfloat16(f); }
__device__ __forceinline__ float bf2f(unsigned short h) {
  unsigned u = ((unsigned)h) << 16;
  return __uint_as_float(u);
}
__device__ __forceinline__ short f2bs(float f) {
  __hip_bfloat16 h = __float2bfloat16(f);
  return *reinterpret_cast<short*>(&h);
}

// ---------------- prep: bf16 weights, packed coords (f32+f64), zero accumulators ----------------
__global__ void prep_kernel(const float* __restrict__ coords,
                            const float* __restrict__ W1,
                            const float* __restrict__ W2,
                            const float* __restrict__ W3,
                            __hip_bfloat16* __restrict__ wc1, __hip_bfloat16* __restrict__ wc2,
                            __hip_bfloat16* __restrict__ wb3,
                            float4* __restrict__ cpk, double4* __restrict__ cpk64,
                            float* __restrict__ acc) {
  int tid = blockIdx.x * 256 + threadIdx.x;
  if (tid < 32768) {                       // wc1 [256][128]
    int o = tid >> 7, i = tid & 127;
    float v;
    if (o < 128) v = W1[o * 256 + i] - W1[o * 256 + 128 + i];
    else         v = W1[(o - 128) * 256 + 128 + i];
    wc1[tid] = ftob(v);
  } else if (tid < 32768 + 65536) {        // wc2 [512][128]
    int t2 = tid - 32768;
    int o = t2 >> 7, i = t2 & 127;
    float v;
    if (o < 256) v = W2[o * 256 + i] - W2[o * 256 + 128 + i];
    else         v = W2[(o - 256) * 256 + 128 + i];
    wc2[t2] = ftob(v);
  } else if (tid < 98304 + 65536) {        // wb3 [128][512] direct cast
    int t2 = tid - 98304;
    wb3[t2] = ftob(W3[t2]);
  } else if (tid < 163840 + B_ * N_) {     // packed coords
    int q = tid - 163840;
    int b = q >> 13, n = q & (N_ - 1);
    float x = coords[(b * 3 + 0) * N_ + n];
    float y = coords[(b * 3 + 1) * N_ + n];
    float z = coords[(b * 3 + 2) * N_ + n];
    float sq = __fadd_rn(__fadd_rn(__fmul_rn(x, x), __fmul_rn(y, y)), __fmul_rn(z, z));
    cpk[q] = make_float4(x, y, z, sq);
    double xd = (double)x, yd = (double)y, zd = (double)z;
    double sqd = (xd * xd + yd * yd) + zd * zd;
    cpk64[q] = make_double4(xd, yd, zd, sqd);
  } else if (tid < 180224 + 2048) {        // acc zeros
    acc[tid - 180224] = 0.f;
  }
}

// ---------------- transpose x0 (B,128,N) f32 -> x3t[b][n][0:128] bf16 (ld 512) ----------------
__global__ __launch_bounds__(256) void transpose_kernel(const float* __restrict__ x0,
                                                        __hip_bfloat16* __restrict__ x3t) {
  __shared__ float tile[64 * 68];
  int b = blockIdx.z, c0 = blockIdx.y * 64, n0 = blockIdx.x * 64;
  int t = threadIdx.x;
  int r = t >> 4;          // 0..15
  int c4 = (t & 15) * 4;   // 0..60
#pragma unroll
  for (int i = 0; i < 4; ++i) {
    int row = r + i * 16;  // c-local
    float4 v = *(const float4*)&x0[((size_t)(b * C_ + c0 + row)) * N_ + n0 + c4];
    *(float4*)&tile[row * 68 + c4] = v;   // tile[c_local][n_local]
  }
  __syncthreads();
#pragma unroll
  for (int i = 0; i < 4; ++i) {
    int nl = r + i * 16;   // n-local
    __hip_bfloat16* dst = &x3t[((size_t)(b * N_ + n0 + nl)) * 512 + c0 + c4];
    dst[0] = ftob(tile[(c4 + 0) * 68 + nl]);
    dst[1] = ftob(tile[(c4 + 1) * 68 + nl]);
    dst[2] = ftob(tile[(c4 + 2) * 68 + nl]);
    dst[3] = ftob(tile[(c4 + 3) * 68 + nl]);
  }
}

// value-only ascending bitonic over 64 lanes; returns 17th-smallest (index 16)
__device__ __forceinline__ float thresh17(float v, int lane) {
#pragma unroll
  for (int k2 = 2; k2 <= 64; k2 <<= 1) {
#pragma unroll
    for (int j = k2 >> 1; j > 0; j >>= 1) {
      float o = __shfl_xor(v, j, 64);
      bool up = ((lane & k2) == 0);
      bool lower = ((lane & j) == 0);
      v = ((lower == up)) ? fminf(v, o) : fmaxf(v, o);
    }
  }
  return __shfl(v, 16, 64);
}

// ascending bitonic sort of 64 double (d, ix) pairs across a wave, key (d, then ix)
__device__ __forceinline__ void bsort64d(double& d, int& ix, int lane) {
#pragma unroll
  for (int k2 = 2; k2 <= 64; k2 <<= 1) {
#pragma unroll
    for (int j = k2 >> 1; j > 0; j >>= 1) {
      double od = __shfl_xor(d, j, 64);
      int oi = __shfl_xor(ix, j, 64);
      bool up = ((lane & k2) == 0);
      bool lower = ((lane & j) == 0);
      bool takeMin = (lower == up);
      bool less = (od < d) || (od == d && oi < ix);
      if (takeMin == less) { d = od; ix = oi; }
    }
  }
}

// ---------------- KNN: Q=2 queries/wave; double-buffered LDS tiles; exact-f64 select ----------------
// R17: Q=4 staging hit the 50% grid occupancy cap (4096 waves) and was barrier-bound
// (VALUBusy 49% @ 38% occ). Q=2 -> 8192 waves (100% cap); block-staged 256-candidate
// tiles double-buffered (1 barrier/tile); traffic 512 MB (~15us L2) vs R10's 2.1 GB.
// Same proxy bits => identical survivor sets; final select exact-f64.
__global__ __launch_bounds__(256) void knn_kernel(const float4* __restrict__ cpk,
                                                  const double4* __restrict__ cpk64,
                                                  int* __restrict__ idxout) {
  __shared__ float4 ctile[2][256];
  __shared__ int scnt[4][2];
  __shared__ int sii[4][2][128];
  int t = threadIdx.x;
  int lane = t & 63;
  int wv = t >> 6;
  int q0 = (blockIdx.x * 4 + wv) * 2;     // 2 consecutive queries per wave
  int b = q0 >> 13;                        // 8 queries/block: never straddles batch
  const float4* cb = cpk + (size_t)b * N_;
  const double4* cb64 = cpk64 + (size_t)b * N_;
  float4 me0 = cpk[q0], me1 = cpk[q0 + 1];
  float a0x = -2.f * me0.x, a0y = -2.f * me0.y, a0z = -2.f * me0.z;
  float a1x = -2.f * me1.x, a1y = -2.f * me1.y, a1z = -2.f * me1.z;

  if (lane < 2) scnt[wv][lane] = 0;

  // Phase A: double-buffered tile scan, 2 proxy mins
  float m0 = INF_, m1 = INF_;
  ctile[0][t] = cb[t];
  __syncthreads();
  for (int tb = 0; tb < 32; ++tb) {
    if (tb + 1 < 32) ctile[(tb + 1) & 1][t] = cb[(tb + 1) * 256 + t];
    const float4* cc = ctile[tb & 1];
#pragma unroll
    for (int i = 0; i < 4; ++i) {
      float4 c = cc[i * 64 + lane];
      m0 = fminf(m0, fmaf(a0z, c.z, fmaf(a0y, c.y, fmaf(a0x, c.x, c.w))));
      m1 = fminf(m1, fmaf(a1z, c.z, fmaf(a1y, c.y, fmaf(a1x, c.x, c.w))));
    }
    __syncthreads();
  }
  float T0 = thresh17(m0, lane) + 1e-3f;
  float T1 = thresh17(m1, lane) + 1e-3f;

  // Phase B: double-buffered re-scan; rare branch; LDS atomic compaction
  ctile[0][t] = cb[t];
  __syncthreads();
  for (int tb = 0; tb < 32; ++tb) {
    if (tb + 1 < 32) ctile[(tb + 1) & 1][t] = cb[(tb + 1) * 256 + t];
    const float4* cc = ctile[tb & 1];
#pragma unroll
    for (int i = 0; i < 4; ++i) {
      float4 c = cc[i * 64 + lane];
      float p0 = fmaf(a0z, c.z, fmaf(a0y, c.y, fmaf(a0x, c.x, c.w)));
      float p1 = fmaf(a1z, c.z, fmaf(a1y, c.y, fmaf(a1x, c.x, c.w)));
      bool h0 = p0 <= T0, h1 = p1 <= T1;
      if (h0 | h1) {
        int m = tb * 256 + i * 64 + lane;
        if (h0) { int p = atomicAdd(&scnt[wv][0], 1); if (p < 128) sii[wv][0][p] = m; }
        if (h1) { int p = atomicAdd(&scnt[wv][1], 1); if (p < 128) sii[wv][1][p] = m; }
      }
    }
    __syncthreads();
  }

  // Phase C: per query, exact f64 on survivors; (d64, idx)-lex bitonic select of 16
#pragma unroll 1
  for (int j = 0; j < 2; ++j) {
    int q = q0 + j;
    int n = q & (N_ - 1);
    int cnt = scnt[wv][j] < 128 ? scnt[wv][j] : 128;
    double4 me64 = cb64[n];
    double d1 = 1e300; int ix1 = 0x7FFFFFFF;
    if (lane < cnt) {
      int m = sii[wv][j][lane];
      if (m != n) {
        double4 c = cb64[m];
        double dot = (me64.x * c.x + me64.y * c.y) + me64.z * c.z;
        d1 = (me64.w + c.w) - 2.0 * dot;
        ix1 = m;
      }
    }
    bsort64d(d1, ix1, lane);
    if (cnt > 64) {
      double d2 = 1e300; int ix2 = 0x7FFFFFFF;
      if (lane + 64 < cnt) {
        int m = sii[wv][j][lane + 64];
        if (m != n) {
          double4 c = cb64[m];
          double dot = (me64.x * c.x + me64.y * c.y) + me64.z * c.z;
          d2 = (me64.w + c.w) - 2.0 * dot;
          ix2 = m;
        }
      }
      bsort64d(d2, ix2, lane);
      int src = (lane - 16) & 63;
      double dB = __shfl(d2, src, 64);
      int iB = __shfl(ix2, src, 64);
      double nd = (lane < 16) ? d1 : ((lane < 32) ? dB : 1e300);
      int nix = (lane < 16) ? ix1 : ((lane < 32) ? iB : 0x7FFFFFFF);
      bsort64d(nd, nix, lane);
      d1 = nd; ix1 = nix;
    }
    if (lane < 16) idxout[(size_t)q * 16 + lane] = ix1;
  }
}

// ---------------- MFMA bf16 GEMM with optional on-load instance-norm+leaky of A ----------------
// NORM=0: plain. NORM=1: all K channels normalized from nacc[(b*128+k)*2] (gemm2).
// NORM=2: concat mode (gemm3): k<128 identity; 128..255 -> acc1; 256..511 -> acc2 (nacc+512).
// C/D layout: col=lane&15, row=(lane>>4)*4+reg (guide m89/m91). OUT = bf16 or f32.
template <typename OUT, int NORM>
__global__ __launch_bounds__(256) void gemm_mfma(const __hip_bfloat16* __restrict__ X, int ldx,
                                                 const __hip_bfloat16* __restrict__ W, int ldw,
                                                 OUT* __restrict__ Cc, int ldc, int Ktot,
                                                 const float* __restrict__ nacc) {
  __shared__ short As[64 * 40];          // 64 rows x 32 k, pad to 40
  int b = blockIdx.z;
  int n0 = blockIdx.x * 64, o0 = blockIdx.y * 64;
  int t = threadIdx.x;
  int lane = t & 63, wv = t >> 6;
  int nh = (wv & 1) * 32, oh = (wv >> 1) * 32;
  const __hip_bfloat16* Xb = X + (size_t)(b * N_ + n0) * ldx;
  f32x4 acc00 = {0.f, 0.f, 0.f, 0.f}, acc01 = acc00, acc10 = acc00, acc11 = acc00;
  int sr = t >> 2;            // 0..63 staging row
  int sc = (t & 3) * 8;       // 0,8,16,24
  int arow = lane & 15;
  int kq = (lane >> 4) * 8;
  for (int kt = 0; kt < Ktot; kt += 32) {
    short8 av = *(const short8*)&Xb[(size_t)sr * ldx + kt + sc];
    if constexpr (NORM != 0) {
      int k = kt + sc;                    // first of 8 consecutive channels, same region
      const float* pa = nullptr;
      if constexpr (NORM == 2) {
        if (k >= 128 && k < 256) pa = nacc + ((size_t)b * 128 + (k - 128)) * 2;
        else if (k >= 256)       pa = nacc + 512 + ((size_t)b * 256 + (k - 256)) * 2;
      } else {
        pa = nacc + ((size_t)b * 128 + k) * 2;
      }
      if (pa) {
        const float inv = 1.f / (float)NK_;
        short8 outv;
#pragma unroll
        for (int j = 0; j < 8; ++j) {
          float s1 = pa[2 * j], s2 = pa[2 * j + 1];
          float mean = s1 * inv;
          float var = fmaf(s2, inv, -mean * mean);
          float rs = rsqrtf(var + EPS_);
          float v = bf2f((unsigned short)av[j]);
          float y = (v - mean) * rs;
          y = y > 0.f ? y : SLOPE_ * y;
          outv[j] = f2bs(y);
        }
        av = outv;
      }
    }
    *(short8*)&As[sr * 40 + sc] = av;
    __syncthreads();
    short8 a0 = *(const short8*)&As[(nh + arow) * 40 + kq];
    short8 a1 = *(const short8*)&As[(nh + 16 + arow) * 40 + kq];
    const __hip_bfloat16* Wp = W + (size_t)(o0 + oh + arow) * ldw + kt + kq;
    short8 b0 = *(const short8*)&Wp[0];
    short8 b1 = *(const short8*)&Wp[16 * (size_t)ldw];
    acc00 = __builtin_amdgcn_mfma_f32_16x16x32_bf16(a0, b0, acc00, 0, 0, 0);
    acc01 = __builtin_amdgcn_mfma_f32_16x16x32_bf16(a0, b1, acc01, 0, 0, 0);
    acc10 = __builtin_amdgcn_mfma_f32_16x16x32_bf16(a1, b0, acc10, 0, 0, 0);
    acc11 = __builtin_amdgcn_mfma_f32_16x16x32_bf16(a1, b1, acc11, 0, 0, 0);
    __syncthreads();
  }
  int crow = (lane >> 4) * 4;
  int ccol = lane & 15;
#pragma unroll
  for (int r = 0; r < 4; ++r) {
    size_t row0 = (size_t)(b * N_ + n0 + nh + crow + r) * ldc + o0 + oh;
    size_t row1 = (size_t)(b * N_ + n0 + nh + 16 + crow + r) * ldc + o0 + oh;
    if constexpr (sizeof(OUT) == 4) {
      Cc[row0 + ccol]      = acc00[r];
      Cc[row0 + 16 + ccol] = acc01[r];
      Cc[row1 + ccol]      = acc10[r];
      Cc[row1 + 16 + ccol] = acc11[r];
    } else {
      Cc[row0 + ccol]      = ftob(acc00[r]);
      Cc[row0 + 16 + ccol] = ftob(acc01[r]);
      Cc[row1 + ccol]      = ftob(acc10[r]);
      Cc[row1 + 16 + ccol] = ftob(acc11[r]);
    }
  }
}

// ---------------- edge gather + max/sum/sumsq: bf16 PQ, 2 channels/thread, 64-query blocks ----------------
// (R11-proven grid: dim3(128,2); 16-query chunking thrashed L2 — see R13 post-mortem)
template <int CO>
__global__ __launch_bounds__(256) void edge_kernel(const __hip_bfloat16* __restrict__ PQ,
                                                   const int* __restrict__ idx,
                                                   __hip_bfloat16* __restrict__ Mout,  // ld 512
                                                   float* __restrict__ acc) {
  constexpr int CP = CO / 2;         // channel pairs
  constexpr int NG = 256 / CP;       // query groups (CO=128 -> 4, CO=256 -> 2)
  __shared__ float r1a[256], r1b[256], r2a[256], r2b[256];
  int b = blockIdx.y;
  int n0 = blockIdx.x * 64;
  int t = threadIdx.x;
  int oc = t & (CP - 1);
  int o2 = oc * 2;
  int qg = t / CP;
  float s1a = 0.f, s1b = 0.f, s2a = 0.f, s2b = 0.f;
  const __hip_bfloat16* PQb = PQ + (size_t)b * N_ * (2 * CO);
  for (int qq = qg; qq < 64; qq += NG) {
    int n = n0 + qq;
    const int4* ip = (const int4*)&idx[(size_t)(b * N_ + n) * 16];
    int4 i0 = ip[0], i1 = ip[1], i2 = ip[2], i3 = ip[3];
    unsigned pu = *(const unsigned*)&PQb[(size_t)n * (2 * CO) + o2];
    float pa = bf2f((unsigned short)(pu & 0xFFFF));
    float pb = bf2f((unsigned short)(pu >> 16));
    float hma = -INF_, hmb = -INF_;
#define EDGE_STEP(mm)                                                         \
    { int mc = (mm) & (N_ - 1);                                               \
      unsigned vu = *(const unsigned*)&PQb[(size_t)mc * (2 * CO) + CO + o2];  \
      float ha = pa + bf2f((unsigned short)(vu & 0xFFFF));                    \
      float hb = pb + bf2f((unsigned short)(vu >> 16));                       \
      hma = fmaxf(hma, ha); s1a += ha; s2a = fmaf(ha, ha, s2a);               \
      hmb = fmaxf(hmb, hb); s1b += hb; s2b = fmaf(hb, hb, s2b); }
    EDGE_STEP(i0.x) EDGE_STEP(i0.y) EDGE_STEP(i0.z) EDGE_STEP(i0.w)
    EDGE_STEP(i1.x) EDGE_STEP(i1.y) EDGE_STEP(i1.z) EDGE_STEP(i1.w)
    EDGE_STEP(i2.x) EDGE_STEP(i2.y) EDGE_STEP(i2.z) EDGE_STEP(i2.w)
    EDGE_STEP(i3.x) EDGE_STEP(i3.y) EDGE_STEP(i3.z) EDGE_STEP(i3.w)
#undef EDGE_STEP
    __hip_bfloat162 hh;
    hh.x = ftob(hma); hh.y = ftob(hmb);
    *(__hip_bfloat162*)&Mout[(size_t)(b * N_ + n) * 512 + o2] = hh;
  }
  r1a[t] = s1a; r1b[t] = s1b; r2a[t] = s2a; r2b[t] = s2b;
  __syncthreads();
  if (t < CP) {
#pragma unroll
    for (int g = 1; g < NG; ++g) {
      s1a += r1a[t + g * CP]; s1b += r1b[t + g * CP];
      s2a += r2a[t + g * CP]; s2b += r2b[t + g * CP];
    }
    atomicAdd(&acc[(b * CO + o2) * 2 + 0], s1a);
    atomicAdd(&acc[(b * CO + o2) * 2 + 1], s2a);
    atomicAdd(&acc[(b * CO + o2 + 1) * 2 + 0], s1b);
    atomicAdd(&acc[(b * CO + o2 + 1) * 2 + 1], s2b);
  }
}

// ---------------- column sums for final inorm (32-row chunks) ----------------
__global__ __launch_bounds__(256) void colred_kernel(const float* __restrict__ H,
                                                     float* __restrict__ acc3) {
  __shared__ float r1[256], r2[256];
  int b = blockIdx.y;
  int n0 = blockIdx.x * 32;
  int t = threadIdx.x;
  int o = t & 127, half = t >> 7;
  float s1 = 0.f, s2 = 0.f;
  for (int i = 0; i < 16; ++i) {
    int n = n0 + half * 16 + i;
    float v = H[(size_t)(b * N_ + n) * 128 + o];
    s1 += v; s2 = fmaf(v, v, s2);
  }
  r1[t] = s1; r2[t] = s2;
  __syncthreads();
  if (t < 128) {
    s1 = r1[t] + r1[t + 128];
    s2 = r2[t] + r2[t + 128];
    atomicAdd(&acc3[(b * 128 + o) * 2 + 0], s1);
    atomicAdd(&acc3[(b * 128 + o) * 2 + 1], s2);
  }
}

// ---------------- final: norm + leaky + transpose to (B,128,N) f32 (32-row chunks) ----------------
__global__ __launch_bounds__(256) void final_kernel(const float* __restrict__ H,
                                                    const float* __restrict__ acc3,
                                                    float* __restrict__ out) {
  __shared__ float tile[32 * 132];
  int b = blockIdx.y, n0 = blockIdx.x * 32;
  int t = threadIdx.x;
  int r = t >> 3;           // 0..31
  int c8 = t & 7;           // 0..7
#pragma unroll
  for (int i = 0; i < 4; ++i) {
    int col4 = (c8 + i * 8) * 4;   // 0..124
    *(float4*)&tile[r * 132 + col4] = *(const float4*)&H[(size_t)(b * N_ + n0 + r) * 128 + col4];
  }
  __syncthreads();
  int o = t >> 1;
  int nh = (t & 1) * 16;
  float s1 = acc3[(b * 128 + o) * 2], s2 = acc3[(b * 128 + o) * 2 + 1];
  const float inv = 1.f / (float)N_;
  float mean = s1 * inv;
  float var = fmaf(s2, inv, -mean * mean);
  float rs = rsqrtf(var + EPS_);
#pragma unroll
  for (int i = 0; i < 16; ++i) {
    int nl = nh + i;
    float v = tile[nl * 132 + o];
    float y = (v - mean) * rs;
    y = y > 0.f ? y : SLOPE_ * y;
    out[(size_t)(b * 128 + o) * N_ + n0 + nl] = y;
  }
}

extern "C" void kernel_launch(void* const* d_in, const int* in_sizes, int n_in,
                              void* d_out, int out_size, void* d_ws, size_t ws_size,
                              hipStream_t stream) {
  const float* coords = (const float*)d_in[0];
  const float* feats = (const float*)d_in[1];
  const float* W1 = (const float*)d_in[2];
  const float* W2 = (const float*)d_in[3];
  const float* W3 = (const float*)d_in[4];
  char* ws = (char*)d_ws;
  int* idx = (int*)(ws + OFF_IDX);
  float4* cpk = (float4*)(ws + OFF_CPK);
  double4* cpk64 = (double4*)(ws + OFF_CPK64);
  float* acc = (float*)(ws + OFF_ACC);  // acc1 @ +0, acc2 @ +512, acc3 @ +1536 (floats)
  __hip_bfloat16* wc1 = (__hip_bfloat16*)(ws + OFF_WC1);
  __hip_bfloat16* wc2 = (__hip_bfloat16*)(ws + OFF_WC2);
  __hip_bfloat16* wb3 = (__hip_bfloat16*)(ws + OFF_WB3);
  __hip_bfloat16* x3t = (__hip_bfloat16*)(ws + OFF_X3T);
  __hip_bfloat16* pqb = (__hip_bfloat16*)(ws + OFF_PQ);  // pq1/pq2 bf16
  float* ht = (float*)(ws + OFF_PQ);                     // ht f32 aliases (pq2 dead by then)

  prep_kernel<<<712, 256, 0, stream>>>(coords, W1, W2, W3, wc1, wc2, wb3, cpk, cpk64, acc);
  transpose_kernel<<<dim3(128, 2, 2), 256, 0, stream>>>(feats, x3t);
  knn_kernel<<<2048, 256, 0, stream>>>(cpk, cpk64, idx);
  // block 1: pqb[b][n][0:128]=P1, [128:256]=Q1
  gemm_mfma<__hip_bfloat16, 0><<<dim3(128, 4, 2), 256, 0, stream>>>(x3t, 512, wc1, 128, pqb, 256, 128, nullptr);
  edge_kernel<128><<<dim3(128, 2), 256, 0, stream>>>(pqb, idx, x3t + 128, acc + 0);
  // block 2: A = raw M1 normalized on load (norm1 from acc1)
  gemm_mfma<__hip_bfloat16, 1><<<dim3(128, 8, 2), 256, 0, stream>>>(x3t + 128, 512, wc2, 128, pqb, 512, 128, acc);
  edge_kernel<256><<<dim3(128, 2), 256, 0, stream>>>(pqb, idx, x3t + 256, acc + 512);
  // final projection: A = concat [x0 | M1 | M2] with norm applied on load (concat mode)
  gemm_mfma<float, 2><<<dim3(128, 2, 2), 256, 0, stream>>>(x3t, 512, wb3, 512, ht, 128, 512, acc);
  colred_kernel<<<dim3(256, 2), 256, 0, stream>>>(ht, acc + 1536);
  final_kernel<<<dim3(256, 2), 256, 0, stream>>>(ht, acc + 1536, (float*)d_out);
}

// Round 19
// 212.094 us; speedup vs baseline: 1.0774x; 1.0774x over previous
//
#include <hip/hip_runtime.h>
#include <hip/hip_bf16.h>
#include <cstdint>
#include <cstddef>

#define B_ 2
#define N_ 8192
#define C_ 128
#define K_ 16
#define NK_ (N_ * K_)
#define EPS_ 1e-5f
#define SLOPE_ 0.2f
#define INF_ 3.0e38f

typedef __attribute__((ext_vector_type(8))) short short8;
typedef __attribute__((ext_vector_type(4))) float f32x4;

// ---------------- workspace layout (bytes) ----------------
static constexpr size_t OFF_IDX   = 0x000000;   // int[B*N*16]          1 MB
static constexpr size_t OFF_CPK   = 0x100000;   // float4[B*N]          256 KB
static constexpr size_t OFF_CPK64 = 0x140000;   // double4[B*N]         512 KB
static constexpr size_t OFF_ACC   = 0x1C0000;   // float[2048]          8 KB
static constexpr size_t OFF_WC1   = 0x1D0000;   // bf16[256*128]        64 KB
static constexpr size_t OFF_WC2   = 0x1E0000;   // bf16[512*128]        128 KB
static constexpr size_t OFF_WB3   = 0x200000;   // bf16[128*512]        128 KB
static constexpr size_t OFF_X3T   = 0x240000;                            // bf16[B*N*512] 16 MB
static constexpr size_t OFF_PQ    = OFF_X3T + (size_t)B_ * N_ * 512 * 2; // 32 MB: pq1/pq2 (bf16) -> ht (f32)
// total ~50.25 MB

__device__ __forceinline__ __hip_bfloat16 ftob(float f) { return __float2bfloat16(f); }
__device__ __forceinline__ float bf2f(unsigned short h) {
  unsigned u = ((unsigned)h) << 16;
  return __uint_as_float(u);
}

// ---------------- prep: bf16 weights, packed coords (f32+f64), zero accumulators ----------------
__global__ void prep_kernel(const float* __restrict__ coords,
                            const float* __restrict__ W1,
                            const float* __restrict__ W2,
                            const float* __restrict__ W3,
                            __hip_bfloat16* __restrict__ wc1, __hip_bfloat16* __restrict__ wc2,
                            __hip_bfloat16* __restrict__ wb3,
                            float4* __restrict__ cpk, double4* __restrict__ cpk64,
                            float* __restrict__ acc) {
  int tid = blockIdx.x * 256 + threadIdx.x;
  if (tid < 32768) {                       // wc1 [256][128]
    int o = tid >> 7, i = tid & 127;
    float v;
    if (o < 128) v = W1[o * 256 + i] - W1[o * 256 + 128 + i];
    else         v = W1[(o - 128) * 256 + 128 + i];
    wc1[tid] = ftob(v);
  } else if (tid < 32768 + 65536) {        // wc2 [512][128]
    int t2 = tid - 32768;
    int o = t2 >> 7, i = t2 & 127;
    float v;
    if (o < 256) v = W2[o * 256 + i] - W2[o * 256 + 128 + i];
    else         v = W2[(o - 256) * 256 + 128 + i];
    wc2[t2] = ftob(v);
  } else if (tid < 98304 + 65536) {        // wb3 [128][512] direct cast
    int t2 = tid - 98304;
    wb3[t2] = ftob(W3[t2]);
  } else if (tid < 163840 + B_ * N_) {     // packed coords
    int q = tid - 163840;
    int b = q >> 13, n = q & (N_ - 1);
    float x = coords[(b * 3 + 0) * N_ + n];
    float y = coords[(b * 3 + 1) * N_ + n];
    float z = coords[(b * 3 + 2) * N_ + n];
    float sq = __fadd_rn(__fadd_rn(__fmul_rn(x, x), __fmul_rn(y, y)), __fmul_rn(z, z));
    cpk[q] = make_float4(x, y, z, sq);
    double xd = (double)x, yd = (double)y, zd = (double)z;
    double sqd = (xd * xd + yd * yd) + zd * zd;
    cpk64[q] = make_double4(xd, yd, zd, sqd);
  } else if (tid < 180224 + 2048) {        // acc zeros
    acc[tid - 180224] = 0.f;
  }
}

// ---------------- transpose x0 (B,128,N) f32 -> x3t[b][n][0:128] bf16 (ld 512) ----------------
__global__ __launch_bounds__(256) void transpose_kernel(const float* __restrict__ x0,
                                                        __hip_bfloat16* __restrict__ x3t) {
  __shared__ float tile[64 * 68];
  int b = blockIdx.z, c0 = blockIdx.y * 64, n0 = blockIdx.x * 64;
  int t = threadIdx.x;
  int r = t >> 4;          // 0..15
  int c4 = (t & 15) * 4;   // 0..60
#pragma unroll
  for (int i = 0; i < 4; ++i) {
    int row = r + i * 16;  // c-local
    float4 v = *(const float4*)&x0[((size_t)(b * C_ + c0 + row)) * N_ + n0 + c4];
    *(float4*)&tile[row * 68 + c4] = v;   // tile[c_local][n_local]
  }
  __syncthreads();
#pragma unroll
  for (int i = 0; i < 4; ++i) {
    int nl = r + i * 16;   // n-local
    __hip_bfloat16* dst = &x3t[((size_t)(b * N_ + n0 + nl)) * 512 + c0 + c4];
    dst[0] = ftob(tile[(c4 + 0) * 68 + nl]);
    dst[1] = ftob(tile[(c4 + 1) * 68 + nl]);
    dst[2] = ftob(tile[(c4 + 2) * 68 + nl]);
    dst[3] = ftob(tile[(c4 + 3) * 68 + nl]);
  }
}

// value-only ascending bitonic over 64 lanes; returns 17th-smallest (index 16)
__device__ __forceinline__ float thresh17(float v, int lane) {
#pragma unroll
  for (int k2 = 2; k2 <= 64; k2 <<= 1) {
#pragma unroll
    for (int j = k2 >> 1; j > 0; j >>= 1) {
      float o = __shfl_xor(v, j, 64);
      bool up = ((lane & k2) == 0);
      bool lower = ((lane & j) == 0);
      v = ((lower == up)) ? fminf(v, o) : fmaxf(v, o);
    }
  }
  return __shfl(v, 16, 64);
}

// ascending bitonic sort of 64 double (d, ix) pairs across a wave, key (d, then ix)
__device__ __forceinline__ void bsort64d(double& d, int& ix, int lane) {
#pragma unroll
  for (int k2 = 2; k2 <= 64; k2 <<= 1) {
#pragma unroll
    for (int j = k2 >> 1; j > 0; j >>= 1) {
      double od = __shfl_xor(d, j, 64);
      int oi = __shfl_xor(ix, j, 64);
      bool up = ((lane & k2) == 0);
      bool lower = ((lane & j) == 0);
      bool takeMin = (lower == up);
      bool less = (od < d) || (od == d && oi < ix);
      if (takeMin == less) { d = od; ix = oi; }
    }
  }
}

// ---------------- KNN: Q=4 queries/wave; LDS-staged two-scan proxy + exact-f64 select ----------------
// (R17-proven: 69 us; best of {no-stage 80, Q4-stage 69, Q2-dbuf 88.6})
__global__ __launch_bounds__(256) void knn_kernel(const float4* __restrict__ cpk,
                                                  const double4* __restrict__ cpk64,
                                                  int* __restrict__ idxout) {
  __shared__ float4 ctile[512];
  __shared__ int scnt[4][4];
  __shared__ int sii[4][4][128];
  int t = threadIdx.x;
  int lane = t & 63;
  int wv = t >> 6;
  int q0 = (blockIdx.x * 4 + wv) * 4;     // 4 consecutive queries per wave, same batch
  int b = q0 >> 13;
  const float4* cb = cpk + (size_t)b * N_;
  const double4* cb64 = cpk64 + (size_t)b * N_;
  float4 me0 = cpk[q0], me1 = cpk[q0 + 1], me2 = cpk[q0 + 2], me3 = cpk[q0 + 3];
  float a0x = -2.f * me0.x, a0y = -2.f * me0.y, a0z = -2.f * me0.z;
  float a1x = -2.f * me1.x, a1y = -2.f * me1.y, a1z = -2.f * me1.z;
  float a2x = -2.f * me2.x, a2y = -2.f * me2.y, a2z = -2.f * me2.z;
  float a3x = -2.f * me3.x, a3y = -2.f * me3.y, a3z = -2.f * me3.z;

  if (lane < 4) scnt[wv][lane] = 0;

  // Phase A: LDS-staged scan, 4 proxy mins
  float m0 = INF_, m1 = INF_, m2 = INF_, m3 = INF_;
  for (int tb = 0; tb < 16; ++tb) {
    __syncthreads();
    ctile[t] = cb[tb * 512 + t];
    ctile[t + 256] = cb[tb * 512 + 256 + t];
    __syncthreads();
#pragma unroll
    for (int i = 0; i < 8; ++i) {
      float4 c = ctile[i * 64 + lane];
      m0 = fminf(m0, fmaf(a0z, c.z, fmaf(a0y, c.y, fmaf(a0x, c.x, c.w))));
      m1 = fminf(m1, fmaf(a1z, c.z, fmaf(a1y, c.y, fmaf(a1x, c.x, c.w))));
      m2 = fminf(m2, fmaf(a2z, c.z, fmaf(a2y, c.y, fmaf(a2x, c.x, c.w))));
      m3 = fminf(m3, fmaf(a3z, c.z, fmaf(a3y, c.y, fmaf(a3x, c.x, c.w))));
    }
  }
  float T0 = thresh17(m0, lane) + 1e-3f;
  float T1 = thresh17(m1, lane) + 1e-3f;
  float T2 = thresh17(m2, lane) + 1e-3f;
  float T3 = thresh17(m3, lane) + 1e-3f;

  // Phase B: LDS-staged re-scan; rare branch; LDS atomic compaction
  for (int tb = 0; tb < 16; ++tb) {
    __syncthreads();
    ctile[t] = cb[tb * 512 + t];
    ctile[t + 256] = cb[tb * 512 + 256 + t];
    __syncthreads();
#pragma unroll
    for (int i = 0; i < 8; ++i) {
      float4 c = ctile[i * 64 + lane];
      float p0 = fmaf(a0z, c.z, fmaf(a0y, c.y, fmaf(a0x, c.x, c.w)));
      float p1 = fmaf(a1z, c.z, fmaf(a1y, c.y, fmaf(a1x, c.x, c.w)));
      float p2 = fmaf(a2z, c.z, fmaf(a2y, c.y, fmaf(a2x, c.x, c.w)));
      float p3 = fmaf(a3z, c.z, fmaf(a3y, c.y, fmaf(a3x, c.x, c.w)));
      bool h0 = p0 <= T0, h1 = p1 <= T1, h2 = p2 <= T2, h3 = p3 <= T3;
      if (h0 | h1 | h2 | h3) {
        int m = tb * 512 + i * 64 + lane;
        if (h0) { int p = atomicAdd(&scnt[wv][0], 1); if (p < 128) sii[wv][0][p] = m; }
        if (h1) { int p = atomicAdd(&scnt[wv][1], 1); if (p < 128) sii[wv][1][p] = m; }
        if (h2) { int p = atomicAdd(&scnt[wv][2], 1); if (p < 128) sii[wv][2][p] = m; }
        if (h3) { int p = atomicAdd(&scnt[wv][3], 1); if (p < 128) sii[wv][3][p] = m; }
      }
    }
  }
  __syncthreads();

  // Phase C: per query, exact f64 on survivors; (d64, idx)-lex bitonic select of 16
#pragma unroll 1
  for (int j = 0; j < 4; ++j) {
    int q = q0 + j;
    int n = q & (N_ - 1);
    int cnt = scnt[wv][j] < 128 ? scnt[wv][j] : 128;
    double4 me64 = cb64[n];
    double d1 = 1e300; int ix1 = 0x7FFFFFFF;
    if (lane < cnt) {
      int m = sii[wv][j][lane];
      if (m != n) {
        double4 c = cb64[m];
        double dot = (me64.x * c.x + me64.y * c.y) + me64.z * c.z;
        d1 = (me64.w + c.w) - 2.0 * dot;
        ix1 = m;
      }
    }
    bsort64d(d1, ix1, lane);
    if (cnt > 64) {
      double d2 = 1e300; int ix2 = 0x7FFFFFFF;
      if (lane + 64 < cnt) {
        int m = sii[wv][j][lane + 64];
        if (m != n) {
          double4 c = cb64[m];
          double dot = (me64.x * c.x + me64.y * c.y) + me64.z * c.z;
          d2 = (me64.w + c.w) - 2.0 * dot;
          ix2 = m;
        }
      }
      bsort64d(d2, ix2, lane);
      int src = (lane - 16) & 63;
      double dB = __shfl(d2, src, 64);
      int iB = __shfl(ix2, src, 64);
      double nd = (lane < 16) ? d1 : ((lane < 32) ? dB : 1e300);
      int nix = (lane < 16) ? ix1 : ((lane < 32) ? iB : 0x7FFFFFFF);
      bsort64d(nd, nix, lane);
      d1 = nd; ix1 = nix;
    }
    if (lane < 16) idxout[(size_t)q * 16 + lane] = ix1;
  }
}

// ---------------- MFMA bf16 GEMM (plain; norm hoisted to separate kernels per R18 post-mortem) ----------------
// C/D layout: col=lane&15, row=(lane>>4)*4+reg (guide m89/m91). OUT = bf16 or f32.
template <typename OUT>
__global__ __launch_bounds__(256) void gemm_mfma(const __hip_bfloat16* __restrict__ X, int ldx,
                                                 const __hip_bfloat16* __restrict__ W, int ldw,
                                                 OUT* __restrict__ Cc, int ldc, int Ktot) {
  __shared__ short As[64 * 40];          // 64 rows x 32 k, pad to 40
  int b = blockIdx.z;
  int n0 = blockIdx.x * 64, o0 = blockIdx.y * 64;
  int t = threadIdx.x;
  int lane = t & 63, wv = t >> 6;
  int nh = (wv & 1) * 32, oh = (wv >> 1) * 32;
  const __hip_bfloat16* Xb = X + (size_t)(b * N_ + n0) * ldx;
  f32x4 acc00 = {0.f, 0.f, 0.f, 0.f}, acc01 = acc00, acc10 = acc00, acc11 = acc00;
  int sr = t >> 2;            // 0..63 staging row
  int sc = (t & 3) * 8;       // 0,8,16,24
  int arow = lane & 15;
  int kq = (lane >> 4) * 8;
  for (int kt = 0; kt < Ktot; kt += 32) {
    short8 av = *(const short8*)&Xb[(size_t)sr * ldx + kt + sc];
    *(short8*)&As[sr * 40 + sc] = av;
    __syncthreads();
    short8 a0 = *(const short8*)&As[(nh + arow) * 40 + kq];
    short8 a1 = *(const short8*)&As[(nh + 16 + arow) * 40 + kq];
    const __hip_bfloat16* Wp = W + (size_t)(o0 + oh + arow) * ldw + kt + kq;
    short8 b0 = *(const short8*)&Wp[0];
    short8 b1 = *(const short8*)&Wp[16 * (size_t)ldw];
    acc00 = __builtin_amdgcn_mfma_f32_16x16x32_bf16(a0, b0, acc00, 0, 0, 0);
    acc01 = __builtin_amdgcn_mfma_f32_16x16x32_bf16(a0, b1, acc01, 0, 0, 0);
    acc10 = __builtin_amdgcn_mfma_f32_16x16x32_bf16(a1, b0, acc10, 0, 0, 0);
    acc11 = __builtin_amdgcn_mfma_f32_16x16x32_bf16(a1, b1, acc11, 0, 0, 0);
    __syncthreads();
  }
  int crow = (lane >> 4) * 4;
  int ccol = lane & 15;
#pragma unroll
  for (int r = 0; r < 4; ++r) {
    size_t row0 = (size_t)(b * N_ + n0 + nh + crow + r) * ldc + o0 + oh;
    size_t row1 = (size_t)(b * N_ + n0 + nh + 16 + crow + r) * ldc + o0 + oh;
    if constexpr (sizeof(OUT) == 4) {
      Cc[row0 + ccol]      = acc00[r];
      Cc[row0 + 16 + ccol] = acc01[r];
      Cc[row1 + ccol]      = acc10[r];
      Cc[row1 + 16 + ccol] = acc11[r];
    } else {
      Cc[row0 + ccol]      = ftob(acc00[r]);
      Cc[row0 + 16 + ccol] = ftob(acc01[r]);
      Cc[row1 + ccol]      = ftob(acc10[r]);
      Cc[row1 + 16 + ccol] = ftob(acc11[r]);
    }
  }
}

// ---------------- edge gather + max/sum/sumsq: bf16 PQ, 2 channels/thread, 64-query blocks ----------------
template <int CO>
__global__ __launch_bounds__(256) void edge_kernel(const __hip_bfloat16* __restrict__ PQ,
                                                   const int* __restrict__ idx,
                                                   __hip_bfloat16* __restrict__ Mout,  // ld 512
                                                   float* __restrict__ acc) {
  constexpr int CP = CO / 2;         // channel pairs
  constexpr int NG = 256 / CP;       // query groups (CO=128 -> 4, CO=256 -> 2)
  __shared__ float r1a[256], r1b[256], r2a[256], r2b[256];
  int b = blockIdx.y;
  int n0 = blockIdx.x * 64;
  int t = threadIdx.x;
  int oc = t & (CP - 1);
  int o2 = oc * 2;
  int qg = t / CP;
  float s1a = 0.f, s1b = 0.f, s2a = 0.f, s2b = 0.f;
  const __hip_bfloat16* PQb = PQ + (size_t)b * N_ * (2 * CO);
  for (int qq = qg; qq < 64; qq += NG) {
    int n = n0 + qq;
    const int4* ip = (const int4*)&idx[(size_t)(b * N_ + n) * 16];
    int4 i0 = ip[0], i1 = ip[1], i2 = ip[2], i3 = ip[3];
    unsigned pu = *(const unsigned*)&PQb[(size_t)n * (2 * CO) + o2];
    float pa = bf2f((unsigned short)(pu & 0xFFFF));
    float pb = bf2f((unsigned short)(pu >> 16));
    float hma = -INF_, hmb = -INF_;
#define EDGE_STEP(mm)                                                         \
    { int mc = (mm) & (N_ - 1);                                               \
      unsigned vu = *(const unsigned*)&PQb[(size_t)mc * (2 * CO) + CO + o2];  \
      float ha = pa + bf2f((unsigned short)(vu & 0xFFFF));                    \
      float hb = pb + bf2f((unsigned short)(vu >> 16));                       \
      hma = fmaxf(hma, ha); s1a += ha; s2a = fmaf(ha, ha, s2a);               \
      hmb = fmaxf(hmb, hb); s1b += hb; s2b = fmaf(hb, hb, s2b); }
    EDGE_STEP(i0.x) EDGE_STEP(i0.y) EDGE_STEP(i0.z) EDGE_STEP(i0.w)
    EDGE_STEP(i1.x) EDGE_STEP(i1.y) EDGE_STEP(i1.z) EDGE_STEP(i1.w)
    EDGE_STEP(i2.x) EDGE_STEP(i2.y) EDGE_STEP(i2.z) EDGE_STEP(i2.w)
    EDGE_STEP(i3.x) EDGE_STEP(i3.y) EDGE_STEP(i3.z) EDGE_STEP(i3.w)
#undef EDGE_STEP
    __hip_bfloat162 hh;
    hh.x = ftob(hma); hh.y = ftob(hmb);
    *(__hip_bfloat162*)&Mout[(size_t)(b * N_ + n) * 512 + o2] = hh;
  }
  r1a[t] = s1a; r1b[t] = s1b; r2a[t] = s2a; r2b[t] = s2b;
  __syncthreads();
  if (t < CP) {
#pragma unroll
    for (int g = 1; g < NG; ++g) {
      s1a += r1a[t + g * CP]; s1b += r1b[t + g * CP];
      s2a += r2a[t + g * CP]; s2b += r2b[t + g * CP];
    }
    atomicAdd(&acc[(b * CO + o2) * 2 + 0], s1a);
    atomicAdd(&acc[(b * CO + o2) * 2 + 1], s2a);
    atomicAdd(&acc[(b * CO + o2 + 1) * 2 + 0], s1b);
    atomicAdd(&acc[(b * CO + o2 + 1) * 2 + 1], s2b);
  }
}

// ---------------- in-place instance-norm + leaky on bf16 (after max-over-k) ----------------
template <int CO>
__global__ void norm_kernel(__hip_bfloat16* __restrict__ M, const float* __restrict__ acc) {
  int tid = blockIdx.x * 256 + threadIdx.x;  // over B*N*CO
  int o = tid & (CO - 1);
  int bn = tid / CO;
  int b = bn >> 13;
  float s1 = acc[(b * CO + o) * 2], s2 = acc[(b * CO + o) * 2 + 1];
  const float inv = 1.f / (float)NK_;
  float mean = s1 * inv;
  float var = fmaf(s2, inv, -mean * mean);
  float rs = rsqrtf(var + EPS_);
  float v = __bfloat162float(M[(size_t)bn * 512 + o]);
  float y = (v - mean) * rs;
  M[(size_t)bn * 512 + o] = ftob(y > 0.f ? y : SLOPE_ * y);
}

// ---------------- column sums for final inorm (32-row chunks) ----------------
__global__ __launch_bounds__(256) void colred_kernel(const float* __restrict__ H,
                                                     float* __restrict__ acc3) {
  __shared__ float r1[256], r2[256];
  int b = blockIdx.y;
  int n0 = blockIdx.x * 32;
  int t = threadIdx.x;
  int o = t & 127, half = t >> 7;
  float s1 = 0.f, s2 = 0.f;
  for (int i = 0; i < 16; ++i) {
    int n = n0 + half * 16 + i;
    float v = H[(size_t)(b * N_ + n) * 128 + o];
    s1 += v; s2 = fmaf(v, v, s2);
  }
  r1[t] = s1; r2[t] = s2;
  __syncthreads();
  if (t < 128) {
    s1 = r1[t] + r1[t + 128];
    s2 = r2[t] + r2[t + 128];
    atomicAdd(&acc3[(b * 128 + o) * 2 + 0], s1);
    atomicAdd(&acc3[(b * 128 + o) * 2 + 1], s2);
  }
}

// ---------------- final: norm + leaky + transpose to (B,128,N) f32 (32-row chunks) ----------------
__global__ __launch_bounds__(256) void final_kernel(const float* __restrict__ H,
                                                    const float* __restrict__ acc3,
                                                    float* __restrict__ out) {
  __shared__ float tile[32 * 132];
  int b = blockIdx.y, n0 = blockIdx.x * 32;
  int t = threadIdx.x;
  int r = t >> 3;           // 0..31
  int c8 = t & 7;           // 0..7
#pragma unroll
  for (int i = 0; i < 4; ++i) {
    int col4 = (c8 + i * 8) * 4;   // 0..124
    *(float4*)&tile[r * 132 + col4] = *(const float4*)&H[(size_t)(b * N_ + n0 + r) * 128 + col4];
  }
  __syncthreads();
  int o = t >> 1;
  int nh = (t & 1) * 16;
  float s1 = acc3[(b * 128 + o) * 2], s2 = acc3[(b * 128 + o) * 2 + 1];
  const float inv = 1.f / (float)N_;
  float mean = s1 * inv;
  float var = fmaf(s2, inv, -mean * mean);
  float rs = rsqrtf(var + EPS_);
#pragma unroll
  for (int i = 0; i < 16; ++i) {
    int nl = nh + i;
    float v = tile[nl * 132 + o];
    float y = (v - mean) * rs;
    y = y > 0.f ? y : SLOPE_ * y;
    out[(size_t)(b * 128 + o) * N_ + n0 + nl] = y;
  }
}

extern "C" void kernel_launch(void* const* d_in, const int* in_sizes, int n_in,
                              void* d_out, int out_size, void* d_ws, size_t ws_size,
                              hipStream_t stream) {
  const float* coords = (const float*)d_in[0];
  const float* feats = (const float*)d_in[1];
  const float* W1 = (const float*)d_in[2];
  const float* W2 = (const float*)d_in[3];
  const float* W3 = (const float*)d_in[4];
  char* ws = (char*)d_ws;
  int* idx = (int*)(ws + OFF_IDX);
  float4* cpk = (float4*)(ws + OFF_CPK);
  double4* cpk64 = (double4*)(ws + OFF_CPK64);
  float* acc = (float*)(ws + OFF_ACC);  // acc1 @ +0, acc2 @ +512, acc3 @ +1536 (floats)
  __hip_bfloat16* wc1 = (__hip_bfloat16*)(ws + OFF_WC1);
  __hip_bfloat16* wc2 = (__hip_bfloat16*)(ws + OFF_WC2);
  __hip_bfloat16* wb3 = (__hip_bfloat16*)(ws + OFF_WB3);
  __hip_bfloat16* x3t = (__hip_bfloat16*)(ws + OFF_X3T);
  __hip_bfloat16* pqb = (__hip_bfloat16*)(ws + OFF_PQ);  // pq1/pq2 bf16
  float* ht = (float*)(ws + OFF_PQ);                     // ht f32 aliases (pq2 dead by then)

  prep_kernel<<<712, 256, 0, stream>>>(coords, W1, W2, W3, wc1, wc2, wb3, cpk, cpk64, acc);
  transpose_kernel<<<dim3(128, 2, 2), 256, 0, stream>>>(feats, x3t);
  knn_kernel<<<1024, 256, 0, stream>>>(cpk, cpk64, idx);
  // block 1: pqb[b][n][0:128]=P1, [128:256]=Q1
  gemm_mfma<__hip_bfloat16><<<dim3(128, 4, 2), 256, 0, stream>>>(x3t, 512, wc1, 128, pqb, 256, 128);
  edge_kernel<128><<<dim3(128, 2), 256, 0, stream>>>(pqb, idx, x3t + 128, acc + 0);
  norm_kernel<128><<<(B_ * N_ * 128) / 256, 256, 0, stream>>>(x3t + 128, acc + 0);
  // block 2: pqb[b][n][0:256]=P2, [256:512]=Q2
  gemm_mfma<__hip_bfloat16><<<dim3(128, 8, 2), 256, 0, stream>>>(x3t + 128, 512, wc2, 128, pqb, 512, 128);
  edge_kernel<256><<<dim3(128, 2), 256, 0, stream>>>(pqb, idx, x3t + 256, acc + 512);
  norm_kernel<256><<<(B_ * N_ * 256) / 256, 256, 0, stream>>>(x3t + 256, acc + 512);
  // final projection + inorm; ht aliases pq region (pq2 dead)
  gemm_mfma<float><<<dim3(128, 2, 2), 256, 0, stream>>>(x3t, 512, wb3, 512, ht, 128, 512);
  colred_kernel<<<dim3(256, 2), 256, 0, stream>>>(ht, acc + 1536);
  final_kernel<<<dim3(256, 2), 256, 0, stream>>>(ht, acc + 1536, (float*)d_out);
}

// Round 20
// 202.422 us; speedup vs baseline: 1.1289x; 1.0478x over previous
//
#include <hip/hip_runtime.h>
#include <hip/hip_bf16.h>
#include <cstdint>
#include <cstddef>

#define B_ 2
#define N_ 8192
#define C_ 128
#define K_ 16
#define NK_ (N_ * K_)
#define EPS_ 1e-5f
#define SLOPE_ 0.2f
#define INF_ 3.0e38f

typedef __attribute__((ext_vector_type(8))) short short8;
typedef __attribute__((ext_vector_type(4))) float f32x4;

// ---------------- workspace layout (bytes) ----------------
static constexpr size_t OFF_IDX   = 0x000000;   // int[B*N*16]          1 MB
static constexpr size_t OFF_CPK   = 0x100000;   // float4[B*N]          256 KB
static constexpr size_t OFF_CPK64 = 0x140000;   // double4[B*N]         512 KB
static constexpr size_t OFF_ACC   = 0x1C0000;   // float[2048]          8 KB
static constexpr size_t OFF_WC1   = 0x1D0000;   // bf16[256*128]        64 KB
static constexpr size_t OFF_WC2   = 0x1E0000;   // bf16[512*128]        128 KB
static constexpr size_t OFF_WB3   = 0x200000;   // bf16[128*512]        128 KB
static constexpr size_t OFF_X3T   = 0x240000;                            // bf16[B*N*512] 16 MB
static constexpr size_t OFF_PQ    = OFF_X3T + (size_t)B_ * N_ * 512 * 2; // 32 MB: pq1/pq2 (bf16) -> ht (f32)
// total ~50.25 MB

__device__ __forceinline__ __hip_bfloat16 ftob(float f) { return __float2bfloat16(f); }
__device__ __forceinline__ float bf2f(unsigned short h) {
  unsigned u = ((unsigned)h) << 16;
  return __uint_as_float(u);
}

// ---------------- prep: bf16 weights, packed coords (f32+f64), zero accumulators ----------------
__global__ void prep_kernel(const float* __restrict__ coords,
                            const float* __restrict__ W1,
                            const float* __restrict__ W2,
                            const float* __restrict__ W3,
                            __hip_bfloat16* __restrict__ wc1, __hip_bfloat16* __restrict__ wc2,
                            __hip_bfloat16* __restrict__ wb3,
                            float4* __restrict__ cpk, double4* __restrict__ cpk64,
                            float* __restrict__ acc) {
  int tid = blockIdx.x * 256 + threadIdx.x;
  if (tid < 32768) {                       // wc1 [256][128]
    int o = tid >> 7, i = tid & 127;
    float v;
    if (o < 128) v = W1[o * 256 + i] - W1[o * 256 + 128 + i];
    else         v = W1[(o - 128) * 256 + 128 + i];
    wc1[tid] = ftob(v);
  } else if (tid < 32768 + 65536) {        // wc2 [512][128]
    int t2 = tid - 32768;
    int o = t2 >> 7, i = t2 & 127;
    float v;
    if (o < 256) v = W2[o * 256 + i] - W2[o * 256 + 128 + i];
    else         v = W2[(o - 256) * 256 + 128 + i];
    wc2[t2] = ftob(v);
  } else if (tid < 98304 + 65536) {        // wb3 [128][512] direct cast
    int t2 = tid - 98304;
    wb3[t2] = ftob(W3[t2]);
  } else if (tid < 163840 + B_ * N_) {     // packed coords
    int q = tid - 163840;
    int b = q >> 13, n = q & (N_ - 1);
    float x = coords[(b * 3 + 0) * N_ + n];
    float y = coords[(b * 3 + 1) * N_ + n];
    float z = coords[(b * 3 + 2) * N_ + n];
    float sq = __fadd_rn(__fadd_rn(__fmul_rn(x, x), __fmul_rn(y, y)), __fmul_rn(z, z));
    cpk[q] = make_float4(x, y, z, sq);
    double xd = (double)x, yd = (double)y, zd = (double)z;
    double sqd = (xd * xd + yd * yd) + zd * zd;
    cpk64[q] = make_double4(xd, yd, zd, sqd);
  } else if (tid < 180224 + 2048) {        // acc zeros
    acc[tid - 180224] = 0.f;
  }
}

// ---------------- transpose x0 (B,128,N) f32 -> x3t[b][n][0:128] bf16 (ld 512) ----------------
__global__ __launch_bounds__(256) void transpose_kernel(const float* __restrict__ x0,
                                                        __hip_bfloat16* __restrict__ x3t) {
  __shared__ float tile[64 * 68];
  int b = blockIdx.z, c0 = blockIdx.y * 64, n0 = blockIdx.x * 64;
  int t = threadIdx.x;
  int r = t >> 4;          // 0..15
  int c4 = (t & 15) * 4;   // 0..60
#pragma unroll
  for (int i = 0; i < 4; ++i) {
    int row = r + i * 16;  // c-local
    float4 v = *(const float4*)&x0[((size_t)(b * C_ + c0 + row)) * N_ + n0 + c4];
    *(float4*)&tile[row * 68 + c4] = v;   // tile[c_local][n_local]
  }
  __syncthreads();
#pragma unroll
  for (int i = 0; i < 4; ++i) {
    int nl = r + i * 16;   // n-local
    __hip_bfloat16* dst = &x3t[((size_t)(b * N_ + n0 + nl)) * 512 + c0 + c4];
    dst[0] = ftob(tile[(c4 + 0) * 68 + nl]);
    dst[1] = ftob(tile[(c4 + 1) * 68 + nl]);
    dst[2] = ftob(tile[(c4 + 2) * 68 + nl]);
    dst[3] = ftob(tile[(c4 + 3) * 68 + nl]);
  }
}

// value-only ascending bitonic over 64 lanes; returns 17th-smallest (index 16)
__device__ __forceinline__ float thresh17(float v, int lane) {
#pragma unroll
  for (int k2 = 2; k2 <= 64; k2 <<= 1) {
#pragma unroll
    for (int j = k2 >> 1; j > 0; j >>= 1) {
      float o = __shfl_xor(v, j, 64);
      bool up = ((lane & k2) == 0);
      bool lower = ((lane & j) == 0);
      v = ((lower == up)) ? fminf(v, o) : fmaxf(v, o);
    }
  }
  return __shfl(v, 16, 64);
}

// ascending bitonic sort of 64 double (d, ix) pairs across a wave, key (d, then ix)
__device__ __forceinline__ void bsort64d(double& d, int& ix, int lane) {
#pragma unroll
  for (int k2 = 2; k2 <= 64; k2 <<= 1) {
#pragma unroll
    for (int j = k2 >> 1; j > 0; j >>= 1) {
      double od = __shfl_xor(d, j, 64);
      int oi = __shfl_xor(ix, j, 64);
      bool up = ((lane & k2) == 0);
      bool lower = ((lane & j) == 0);
      bool takeMin = (lower == up);
      bool less = (od < d) || (od == d && oi < ix);
      if (takeMin == less) { d = od; ix = oi; }
    }
  }
}

// ---------------- KNN: Q=4 queries/wave; 1024-candidate LDS tiles (half the barriers of R17) ----------------
// R17 (512-tiles): 69 us, VALUBusy 50% at 41% occ -> barrier-limited. 8 staging rounds/scan now.
// Same proxy bits => identical survivor sets; final select exact-f64.
__global__ __launch_bounds__(256) void knn_kernel(const float4* __restrict__ cpk,
                                                  const double4* __restrict__ cpk64,
                                                  int* __restrict__ idxout) {
  __shared__ float4 ctile[1024];
  __shared__ int scnt[4][4];
  __shared__ int sii[4][4][128];
  int t = threadIdx.x;
  int lane = t & 63;
  int wv = t >> 6;
  int q0 = (blockIdx.x * 4 + wv) * 4;     // 4 consecutive queries per wave, same batch
  int b = q0 >> 13;
  const float4* cb = cpk + (size_t)b * N_;
  const double4* cb64 = cpk64 + (size_t)b * N_;
  float4 me0 = cpk[q0], me1 = cpk[q0 + 1], me2 = cpk[q0 + 2], me3 = cpk[q0 + 3];
  float a0x = -2.f * me0.x, a0y = -2.f * me0.y, a0z = -2.f * me0.z;
  float a1x = -2.f * me1.x, a1y = -2.f * me1.y, a1z = -2.f * me1.z;
  float a2x = -2.f * me2.x, a2y = -2.f * me2.y, a2z = -2.f * me2.z;
  float a3x = -2.f * me3.x, a3y = -2.f * me3.y, a3z = -2.f * me3.z;

  if (lane < 4) scnt[wv][lane] = 0;

  // Phase A: LDS-staged scan (1024-cand tiles), 4 proxy mins
  float m0 = INF_, m1 = INF_, m2 = INF_, m3 = INF_;
  for (int tb = 0; tb < 8; ++tb) {
    __syncthreads();
    ctile[t]       = cb[tb * 1024 + t];
    ctile[t + 256] = cb[tb * 1024 + 256 + t];
    ctile[t + 512] = cb[tb * 1024 + 512 + t];
    ctile[t + 768] = cb[tb * 1024 + 768 + t];
    __syncthreads();
#pragma unroll
    for (int i = 0; i < 16; ++i) {
      float4 c = ctile[i * 64 + lane];
      m0 = fminf(m0, fmaf(a0z, c.z, fmaf(a0y, c.y, fmaf(a0x, c.x, c.w))));
      m1 = fminf(m1, fmaf(a1z, c.z, fmaf(a1y, c.y, fmaf(a1x, c.x, c.w))));
      m2 = fminf(m2, fmaf(a2z, c.z, fmaf(a2y, c.y, fmaf(a2x, c.x, c.w))));
      m3 = fminf(m3, fmaf(a3z, c.z, fmaf(a3y, c.y, fmaf(a3x, c.x, c.w))));
    }
  }
  float T0 = thresh17(m0, lane) + 1e-3f;
  float T1 = thresh17(m1, lane) + 1e-3f;
  float T2 = thresh17(m2, lane) + 1e-3f;
  float T3 = thresh17(m3, lane) + 1e-3f;

  // Phase B: LDS-staged re-scan; rare branch; LDS atomic compaction
  for (int tb = 0; tb < 8; ++tb) {
    __syncthreads();
    ctile[t]       = cb[tb * 1024 + t];
    ctile[t + 256] = cb[tb * 1024 + 256 + t];
    ctile[t + 512] = cb[tb * 1024 + 512 + t];
    ctile[t + 768] = cb[tb * 1024 + 768 + t];
    __syncthreads();
#pragma unroll
    for (int i = 0; i < 16; ++i) {
      float4 c = ctile[i * 64 + lane];
      float p0 = fmaf(a0z, c.z, fmaf(a0y, c.y, fmaf(a0x, c.x, c.w)));
      float p1 = fmaf(a1z, c.z, fmaf(a1y, c.y, fmaf(a1x, c.x, c.w)));
      float p2 = fmaf(a2z, c.z, fmaf(a2y, c.y, fmaf(a2x, c.x, c.w)));
      float p3 = fmaf(a3z, c.z, fmaf(a3y, c.y, fmaf(a3x, c.x, c.w)));
      bool h0 = p0 <= T0, h1 = p1 <= T1, h2 = p2 <= T2, h3 = p3 <= T3;
      if (h0 | h1 | h2 | h3) {
        int m = tb * 1024 + i * 64 + lane;
        if (h0) { int p = atomicAdd(&scnt[wv][0], 1); if (p < 128) sii[wv][0][p] = m; }
        if (h1) { int p = atomicAdd(&scnt[wv][1], 1); if (p < 128) sii[wv][1][p] = m; }
        if (h2) { int p = atomicAdd(&scnt[wv][2], 1); if (p < 128) sii[wv][2][p] = m; }
        if (h3) { int p = atomicAdd(&scnt[wv][3], 1); if (p < 128) sii[wv][3][p] = m; }
      }
    }
  }
  __syncthreads();

  // Phase C: per query, exact f64 on survivors; (d64, idx)-lex bitonic select of 16
#pragma unroll 1
  for (int j = 0; j < 4; ++j) {
    int q = q0 + j;
    int n = q & (N_ - 1);
    int cnt = scnt[wv][j] < 128 ? scnt[wv][j] : 128;
    double4 me64 = cb64[n];
    double d1 = 1e300; int ix1 = 0x7FFFFFFF;
    if (lane < cnt) {
      int m = sii[wv][j][lane];
      if (m != n) {
        double4 c = cb64[m];
        double dot = (me64.x * c.x + me64.y * c.y) + me64.z * c.z;
        d1 = (me64.w + c.w) - 2.0 * dot;
        ix1 = m;
      }
    }
    bsort64d(d1, ix1, lane);
    if (cnt > 64) {
      double d2 = 1e300; int ix2 = 0x7FFFFFFF;
      if (lane + 64 < cnt) {
        int m = sii[wv][j][lane + 64];
        if (m != n) {
          double4 c = cb64[m];
          double dot = (me64.x * c.x + me64.y * c.y) + me64.z * c.z;
          d2 = (me64.w + c.w) - 2.0 * dot;
          ix2 = m;
        }
      }
      bsort64d(d2, ix2, lane);
      int src = (lane - 16) & 63;
      double dB = __shfl(d2, src, 64);
      int iB = __shfl(ix2, src, 64);
      double nd = (lane < 16) ? d1 : ((lane < 32) ? dB : 1e300);
      int nix = (lane < 16) ? ix1 : ((lane < 32) ? iB : 0x7FFFFFFF);
      bsort64d(nd, nix, lane);
      d1 = nd; ix1 = nix;
    }
    if (lane < 16) idxout[(size_t)q * 16 + lane] = ix1;
  }
}

// ---------------- MFMA bf16 GEMM (plain) ----------------
// C/D layout: col=lane&15, row=(lane>>4)*4+reg (guide m89/m91). OUT = bf16 or f32.
template <typename OUT>
__global__ __launch_bounds__(256) void gemm_mfma(const __hip_bfloat16* __restrict__ X, int ldx,
                                                 const __hip_bfloat16* __restrict__ W, int ldw,
                                                 OUT* __restrict__ Cc, int ldc, int Ktot) {
  __shared__ short As[64 * 40];          // 64 rows x 32 k, pad to 40
  int b = blockIdx.z;
  int n0 = blockIdx.x * 64, o0 = blockIdx.y * 64;
  int t = threadIdx.x;
  int lane = t & 63, wv = t >> 6;
  int nh = (wv & 1) * 32, oh = (wv >> 1) * 32;
  const __hip_bfloat16* Xb = X + (size_t)(b * N_ + n0) * ldx;
  f32x4 acc00 = {0.f, 0.f, 0.f, 0.f}, acc01 = acc00, acc10 = acc00, acc11 = acc00;
  int sr = t >> 2;            // 0..63 staging row
  int sc = (t & 3) * 8;       // 0,8,16,24
  int arow = lane & 15;
  int kq = (lane >> 4) * 8;
  for (int kt = 0; kt < Ktot; kt += 32) {
    short8 av = *(const short8*)&Xb[(size_t)sr * ldx + kt + sc];
    *(short8*)&As[sr * 40 + sc] = av;
    __syncthreads();
    short8 a0 = *(const short8*)&As[(nh + arow) * 40 + kq];
    short8 a1 = *(const short8*)&As[(nh + 16 + arow) * 40 + kq];
    const __hip_bfloat16* Wp = W + (size_t)(o0 + oh + arow) * ldw + kt + kq;
    short8 b0 = *(const short8*)&Wp[0];
    short8 b1 = *(const short8*)&Wp[16 * (size_t)ldw];
    acc00 = __builtin_amdgcn_mfma_f32_16x16x32_bf16(a0, b0, acc00, 0, 0, 0);
    acc01 = __builtin_amdgcn_mfma_f32_16x16x32_bf16(a0, b1, acc01, 0, 0, 0);
    acc10 = __builtin_amdgcn_mfma_f32_16x16x32_bf16(a1, b0, acc10, 0, 0, 0);
    acc11 = __builtin_amdgcn_mfma_f32_16x16x32_bf16(a1, b1, acc11, 0, 0, 0);
    __syncthreads();
  }
  int crow = (lane >> 4) * 4;
  int ccol = lane & 15;
#pragma unroll
  for (int r = 0; r < 4; ++r) {
    size_t row0 = (size_t)(b * N_ + n0 + nh + crow + r) * ldc + o0 + oh;
    size_t row1 = (size_t)(b * N_ + n0 + nh + 16 + crow + r) * ldc + o0 + oh;
    if constexpr (sizeof(OUT) == 4) {
      Cc[row0 + ccol]      = acc00[r];
      Cc[row0 + 16 + ccol] = acc01[r];
      Cc[row1 + ccol]      = acc10[r];
      Cc[row1 + 16 + ccol] = acc11[r];
    } else {
      Cc[row0 + ccol]      = ftob(acc00[r]);
      Cc[row0 + 16 + ccol] = ftob(acc01[r]);
      Cc[row1 + ccol]      = ftob(acc10[r]);
      Cc[row1 + 16 + ccol] = ftob(acc11[r]);
    }
  }
}

// ---------------- edge gather + max/sum/sumsq: bf16 PQ, 2 channels/thread, 64-query blocks ----------------
template <int CO>
__global__ __launch_bounds__(256) void edge_kernel(const __hip_bfloat16* __restrict__ PQ,
                                                   const int* __restrict__ idx,
                                                   __hip_bfloat16* __restrict__ Mout,  // ld 512
                                                   float* __restrict__ acc) {
  constexpr int CP = CO / 2;         // channel pairs
  constexpr int NG = 256 / CP;       // query groups (CO=128 -> 4, CO=256 -> 2)
  __shared__ float r1a[256], r1b[256], r2a[256], r2b[256];
  int b = blockIdx.y;
  int n0 = blockIdx.x * 64;
  int t = threadIdx.x;
  int oc = t & (CP - 1);
  int o2 = oc * 2;
  int qg = t / CP;
  float s1a = 0.f, s1b = 0.f, s2a = 0.f, s2b = 0.f;
  const __hip_bfloat16* PQb = PQ + (size_t)b * N_ * (2 * CO);
  for (int qq = qg; qq < 64; qq += NG) {
    int n = n0 + qq;
    const int4* ip = (const int4*)&idx[(size_t)(b * N_ + n) * 16];
    int4 i0 = ip[0], i1 = ip[1], i2 = ip[2], i3 = ip[3];
    unsigned pu = *(const unsigned*)&PQb[(size_t)n * (2 * CO) + o2];
    float pa = bf2f((unsigned short)(pu & 0xFFFF));
    float pb = bf2f((unsigned short)(pu >> 16));
    float hma = -INF_, hmb = -INF_;
#define EDGE_STEP(mm)                                                         \
    { int mc = (mm) & (N_ - 1);                                               \
      unsigned vu = *(const unsigned*)&PQb[(size_t)mc * (2 * CO) + CO + o2];  \
      float ha = pa + bf2f((unsigned short)(vu & 0xFFFF));                    \
      float hb = pb + bf2f((unsigned short)(vu >> 16));                       \
      hma = fmaxf(hma, ha); s1a += ha; s2a = fmaf(ha, ha, s2a);               \
      hmb = fmaxf(hmb, hb); s1b += hb; s2b = fmaf(hb, hb, s2b); }
    EDGE_STEP(i0.x) EDGE_STEP(i0.y) EDGE_STEP(i0.z) EDGE_STEP(i0.w)
    EDGE_STEP(i1.x) EDGE_STEP(i1.y) EDGE_STEP(i1.z) EDGE_STEP(i1.w)
    EDGE_STEP(i2.x) EDGE_STEP(i2.y) EDGE_STEP(i2.z) EDGE_STEP(i2.w)
    EDGE_STEP(i3.x) EDGE_STEP(i3.y) EDGE_STEP(i3.z) EDGE_STEP(i3.w)
#undef EDGE_STEP
    __hip_bfloat162 hh;
    hh.x = ftob(hma); hh.y = ftob(hmb);
    *(__hip_bfloat162*)&Mout[(size_t)(b * N_ + n) * 512 + o2] = hh;
  }
  r1a[t] = s1a; r1b[t] = s1b; r2a[t] = s2a; r2b[t] = s2b;
  __syncthreads();
  if (t < CP) {
#pragma unroll
    for (int g = 1; g < NG; ++g) {
      s1a += r1a[t + g * CP]; s1b += r1b[t + g * CP];
      s2a += r2a[t + g * CP]; s2b += r2b[t + g * CP];
    }
    atomicAdd(&acc[(b * CO + o2) * 2 + 0], s1a);
    atomicAdd(&acc[(b * CO + o2) * 2 + 1], s2a);
    atomicAdd(&acc[(b * CO + o2 + 1) * 2 + 0], s1b);
    atomicAdd(&acc[(b * CO + o2 + 1) * 2 + 1], s2b);
  }
}

// ---------------- in-place instance-norm + leaky on bf16 (after max-over-k) ----------------
template <int CO>
__global__ void norm_kernel(__hip_bfloat16* __restrict__ M, const float* __restrict__ acc) {
  int tid = blockIdx.x * 256 + threadIdx.x;  // over B*N*CO
  int o = tid & (CO - 1);
  int bn = tid / CO;
  int b = bn >> 13;
  float s1 = acc[(b * CO + o) * 2], s2 = acc[(b * CO + o) * 2 + 1];
  const float inv = 1.f / (float)NK_;
  float mean = s1 * inv;
  float var = fmaf(s2, inv, -mean * mean);
  float rs = rsqrtf(var + EPS_);
  float v = __bfloat162float(M[(size_t)bn * 512 + o]);
  float y = (v - mean) * rs;
  M[(size_t)bn * 512 + o] = ftob(y > 0.f ? y : SLOPE_ * y);
}

// ---------------- column sums for final inorm (R9-proven grid: 64 blocks total) ----------------
__global__ __launch_bounds__(256) void colred_kernel(const float* __restrict__ H,
                                                     float* __restrict__ acc3) {
  __shared__ float r1[256], r2[256];
  int b = blockIdx.y;
  int n0 = blockIdx.x * 256;
  int t = threadIdx.x;
  int o = t & 127, half = t >> 7;
  float s1 = 0.f, s2 = 0.f;
  for (int i = 0; i < 128; ++i) {
    int n = n0 + half * 128 + i;
    float v = H[(size_t)(b * N_ + n) * 128 + o];
    s1 += v; s2 = fmaf(v, v, s2);
  }
  r1[t] = s1; r2[t] = s2;
  __syncthreads();
  if (t < 128) {
    s1 = r1[t] + r1[t + 128];
    s2 = r2[t] + r2[t + 128];
    atomicAdd(&acc3[(b * 128 + o) * 2 + 0], s1);
    atomicAdd(&acc3[(b * 128 + o) * 2 + 1], s2);
  }
}

// ---------------- final: norm + leaky + transpose to (B,128,N) f32 (R9-proven grid) ----------------
__global__ __launch_bounds__(256) void final_kernel(const float* __restrict__ H,
                                                    const float* __restrict__ acc3,
                                                    float* __restrict__ out) {
  __shared__ float tile[64 * 132];
  int b = blockIdx.y, n0 = blockIdx.x * 64;
  int t = threadIdx.x;
  int r = t >> 5;           // 0..7
  int c4 = (t & 31) * 4;    // 0..124
#pragma unroll
  for (int i = 0; i < 8; ++i) {
    int row = r + i * 8;
    *(float4*)&tile[row * 132 + c4] = *(const float4*)&H[(size_t)(b * N_ + n0 + row) * 128 + c4];
  }
  __syncthreads();
  int o = t >> 1;
  int nh = (t & 1) * 32;
  float s1 = acc3[(b * 128 + o) * 2], s2 = acc3[(b * 128 + o) * 2 + 1];
  const float inv = 1.f / (float)N_;
  float mean = s1 * inv;
  float var = fmaf(s2, inv, -mean * mean);
  float rs = rsqrtf(var + EPS_);
#pragma unroll
  for (int i = 0; i < 32; ++i) {
    int nl = nh + i;
    float v = tile[nl * 132 + o];
    float y = (v - mean) * rs;
    y = y > 0.f ? y : SLOPE_ * y;
    out[(size_t)(b * 128 + o) * N_ + n0 + nl] = y;
  }
}

extern "C" void kernel_launch(void* const* d_in, const int* in_sizes, int n_in,
                              void* d_out, int out_size, void* d_ws, size_t ws_size,
                              hipStream_t stream) {
  const float* coords = (const float*)d_in[0];
  const float* feats = (const float*)d_in[1];
  const float* W1 = (const float*)d_in[2];
  const float* W2 = (const float*)d_in[3];
  const float* W3 = (const float*)d_in[4];
  char* ws = (char*)d_ws;
  int* idx = (int*)(ws + OFF_IDX);
  float4* cpk = (float4*)(ws + OFF_CPK);
  double4* cpk64 = (double4*)(ws + OFF_CPK64);
  float* acc = (float*)(ws + OFF_ACC);  // acc1 @ +0, acc2 @ +512, acc3 @ +1536 (floats)
  __hip_bfloat16* wc1 = (__hip_bfloat16*)(ws + OFF_WC1);
  __hip_bfloat16* wc2 = (__hip_bfloat16*)(ws + OFF_WC2);
  __hip_bfloat16* wb3 = (__hip_bfloat16*)(ws + OFF_WB3);
  __hip_bfloat16* x3t = (__hip_bfloat16*)(ws + OFF_X3T);
  __hip_bfloat16* pqb = (__hip_bfloat16*)(ws + OFF_PQ);  // pq1/pq2 bf16
  float* ht = (float*)(ws + OFF_PQ);                     // ht f32 aliases (pq2 dead by then)

  prep_kernel<<<712, 256, 0, stream>>>(coords, W1, W2, W3, wc1, wc2, wb3, cpk, cpk64, acc);
  transpose_kernel<<<dim3(128, 2, 2), 256, 0, stream>>>(feats, x3t);
  knn_kernel<<<1024, 256, 0, stream>>>(cpk, cpk64, idx);
  // block 1: pqb[b][n][0:128]=P1, [128:256]=Q1
  gemm_mfma<__hip_bfloat16><<<dim3(128, 4, 2), 256, 0, stream>>>(x3t, 512, wc1, 128, pqb, 256, 128);
  edge_kernel<128><<<dim3(128, 2), 256, 0, stream>>>(pqb, idx, x3t + 128, acc + 0);
  norm_kernel<128><<<(B_ * N_ * 128) / 256, 256, 0, stream>>>(x3t + 128, acc + 0);
  // block 2: pqb[b][n][0:256]=P2, [256:512]=Q2
  gemm_mfma<__hip_bfloat16><<<dim3(128, 8, 2), 256, 0, stream>>>(x3t + 128, 512, wc2, 128, pqb, 512, 128);
  edge_kernel<256><<<dim3(128, 2), 256, 0, stream>>>(pqb, idx, x3t + 256, acc + 512);
  norm_kernel<256><<<(B_ * N_ * 256) / 256, 256, 0, stream>>>(x3t + 256, acc + 512);
  // final projection + inorm; ht aliases pq region (pq2 dead)
  gemm_mfma<float><<<dim3(128, 2, 2), 256, 0, stream>>>(x3t, 512, wb3, 512, ht, 128, 512);
  colred_kernel<<<dim3(32, 2), 256, 0, stream>>>(ht, acc + 1536);
  final_kernel<<<dim3(128, 2), 256, 0, stream>>>(ht, acc + 1536, (float*)d_out);
}

// Round 21
// 200.515 us; speedup vs baseline: 1.1396x; 1.0095x over previous
//
#include <hip/hip_runtime.h>
#include <hip/hip_bf16.h>
#include <cstdint>
#include <cstddef>

#define B_ 2
#define N_ 8192
#define C_ 128
#define K_ 16
#define NK_ (N_ * K_)
#define EPS_ 1e-5f
#define SLOPE_ 0.2f
#define INF_ 3.0e38f

typedef __attribute__((ext_vector_type(8))) short short8;
typedef __attribute__((ext_vector_type(4))) float f32x4;

// ---------------- workspace layout (bytes) ----------------
static constexpr size_t OFF_IDX   = 0x000000;   // int[B*N*16]          1 MB
static constexpr size_t OFF_CPK   = 0x100000;   // float4[B*N]          256 KB
static constexpr size_t OFF_CPK64 = 0x140000;   // double4[B*N]         512 KB
static constexpr size_t OFF_ACC   = 0x1C0000;   // float[2048]          8 KB
static constexpr size_t OFF_WC1   = 0x1D0000;   // bf16[256*128]        64 KB
static constexpr size_t OFF_WC2   = 0x1E0000;   // bf16[512*128]        128 KB
static constexpr size_t OFF_WB3   = 0x200000;   // bf16[128*512]        128 KB
static constexpr size_t OFF_X3T   = 0x240000;                            // bf16[B*N*512] 16 MB
static constexpr size_t OFF_PQ    = OFF_X3T + (size_t)B_ * N_ * 512 * 2; // 32 MB: pq1/pq2 (bf16) -> ht (f32)
// total ~50.25 MB

__device__ __forceinline__ __hip_bfloat16 ftob(float f) { return __float2bfloat16(f); }
__device__ __forceinline__ float bf2f(unsigned short h) {
  unsigned u = ((unsigned)h) << 16;
  return __uint_as_float(u);
}

// ---------------- prep: bf16 weights, packed coords (f32+f64), zero accumulators ----------------
__global__ void prep_kernel(const float* __restrict__ coords,
                            const float* __restrict__ W1,
                            const float* __restrict__ W2,
                            const float* __restrict__ W3,
                            __hip_bfloat16* __restrict__ wc1, __hip_bfloat16* __restrict__ wc2,
                            __hip_bfloat16* __restrict__ wb3,
                            float4* __restrict__ cpk, double4* __restrict__ cpk64,
                            float* __restrict__ acc) {
  int tid = blockIdx.x * 256 + threadIdx.x;
  if (tid < 32768) {                       // wc1 [256][128]
    int o = tid >> 7, i = tid & 127;
    float v;
    if (o < 128) v = W1[o * 256 + i] - W1[o * 256 + 128 + i];
    else         v = W1[(o - 128) * 256 + 128 + i];
    wc1[tid] = ftob(v);
  } else if (tid < 32768 + 65536) {        // wc2 [512][128]
    int t2 = tid - 32768;
    int o = t2 >> 7, i = t2 & 127;
    float v;
    if (o < 256) v = W2[o * 256 + i] - W2[o * 256 + 128 + i];
    else         v = W2[(o - 256) * 256 + 128 + i];
    wc2[t2] = ftob(v);
  } else if (tid < 98304 + 65536) {        // wb3 [128][512] direct cast
    int t2 = tid - 98304;
    wb3[t2] = ftob(W3[t2]);
  } else if (tid < 163840 + B_ * N_) {     // packed coords
    int q = tid - 163840;
    int b = q >> 13, n = q & (N_ - 1);
    float x = coords[(b * 3 + 0) * N_ + n];
    float y = coords[(b * 3 + 1) * N_ + n];
    float z = coords[(b * 3 + 2) * N_ + n];
    float sq = __fadd_rn(__fadd_rn(__fmul_rn(x, x), __fmul_rn(y, y)), __fmul_rn(z, z));
    cpk[q] = make_float4(x, y, z, sq);
    double xd = (double)x, yd = (double)y, zd = (double)z;
    double sqd = (xd * xd + yd * yd) + zd * zd;
    cpk64[q] = make_double4(xd, yd, zd, sqd);
  } else if (tid < 180224 + 2048) {        // acc zeros
    acc[tid - 180224] = 0.f;
  }
}

// ---------------- transpose x0 (B,128,N) f32 -> x3t[b][n][0:128] bf16 (ld 512) ----------------
__global__ __launch_bounds__(256) void transpose_kernel(const float* __restrict__ x0,
                                                        __hip_bfloat16* __restrict__ x3t) {
  __shared__ float tile[64 * 68];
  int b = blockIdx.z, c0 = blockIdx.y * 64, n0 = blockIdx.x * 64;
  int t = threadIdx.x;
  int r = t >> 4;          // 0..15
  int c4 = (t & 15) * 4;   // 0..60
#pragma unroll
  for (int i = 0; i < 4; ++i) {
    int row = r + i * 16;  // c-local
    float4 v = *(const float4*)&x0[((size_t)(b * C_ + c0 + row)) * N_ + n0 + c4];
    *(float4*)&tile[row * 68 + c4] = v;   // tile[c_local][n_local]
  }
  __syncthreads();
#pragma unroll
  for (int i = 0; i < 4; ++i) {
    int nl = r + i * 16;   // n-local
    __hip_bfloat16* dst = &x3t[((size_t)(b * N_ + n0 + nl)) * 512 + c0 + c4];
    dst[0] = ftob(tile[(c4 + 0) * 68 + nl]);
    dst[1] = ftob(tile[(c4 + 1) * 68 + nl]);
    dst[2] = ftob(tile[(c4 + 2) * 68 + nl]);
    dst[3] = ftob(tile[(c4 + 3) * 68 + nl]);
  }
}

// value-only ascending bitonic over 64 lanes; returns 17th-smallest (index 16)
__device__ __forceinline__ float thresh17(float v, int lane) {
#pragma unroll
  for (int k2 = 2; k2 <= 64; k2 <<= 1) {
#pragma unroll
    for (int j = k2 >> 1; j > 0; j >>= 1) {
      float o = __shfl_xor(v, j, 64);
      bool up = ((lane & k2) == 0);
      bool lower = ((lane & j) == 0);
      v = ((lower == up)) ? fminf(v, o) : fmaxf(v, o);
    }
  }
  return __shfl(v, 16, 64);
}

// ascending bitonic sort of 64 double (d, ix) pairs across a wave, key (d, then ix)
__device__ __forceinline__ void bsort64d(double& d, int& ix, int lane) {
#pragma unroll
  for (int k2 = 2; k2 <= 64; k2 <<= 1) {
#pragma unroll
    for (int j = k2 >> 1; j > 0; j >>= 1) {
      double od = __shfl_xor(d, j, 64);
      int oi = __shfl_xor(ix, j, 64);
      bool up = ((lane & k2) == 0);
      bool lower = ((lane & j) == 0);
      bool takeMin = (lower == up);
      bool less = (od < d) || (od == d && oi < ix);
      if (takeMin == less) { d = od; ix = oi; }
    }
  }
}

// ---------------- KNN: Q=4 queries/wave; 512-cand LDS tiles (measured optimum: 69us) ----------------
// Tile sweep: no-stage 80us, 512-tile 69us, 1024-tile 77us, Q2-dbuf 88.6us.
// Same proxy bits => identical survivor sets; final select exact-f64.
__global__ __launch_bounds__(256) void knn_kernel(const float4* __restrict__ cpk,
                                                  const double4* __restrict__ cpk64,
                                                  int* __restrict__ idxout) {
  __shared__ float4 ctile[512];
  __shared__ int scnt[4][4];
  __shared__ int sii[4][4][128];
  int t = threadIdx.x;
  int lane = t & 63;
  int wv = t >> 6;
  int q0 = (blockIdx.x * 4 + wv) * 4;     // 4 consecutive queries per wave, same batch
  int b = q0 >> 13;
  const float4* cb = cpk + (size_t)b * N_;
  const double4* cb64 = cpk64 + (size_t)b * N_;
  float4 me0 = cpk[q0], me1 = cpk[q0 + 1], me2 = cpk[q0 + 2], me3 = cpk[q0 + 3];
  float a0x = -2.f * me0.x, a0y = -2.f * me0.y, a0z = -2.f * me0.z;
  float a1x = -2.f * me1.x, a1y = -2.f * me1.y, a1z = -2.f * me1.z;
  float a2x = -2.f * me2.x, a2y = -2.f * me2.y, a2z = -2.f * me2.z;
  float a3x = -2.f * me3.x, a3y = -2.f * me3.y, a3z = -2.f * me3.z;

  if (lane < 4) scnt[wv][lane] = 0;

  // Phase A: LDS-staged scan, 4 proxy mins
  float m0 = INF_, m1 = INF_, m2 = INF_, m3 = INF_;
  for (int tb = 0; tb < 16; ++tb) {
    __syncthreads();
    ctile[t] = cb[tb * 512 + t];
    ctile[t + 256] = cb[tb * 512 + 256 + t];
    __syncthreads();
#pragma unroll
    for (int i = 0; i < 8; ++i) {
      float4 c = ctile[i * 64 + lane];
      m0 = fminf(m0, fmaf(a0z, c.z, fmaf(a0y, c.y, fmaf(a0x, c.x, c.w))));
      m1 = fminf(m1, fmaf(a1z, c.z, fmaf(a1y, c.y, fmaf(a1x, c.x, c.w))));
      m2 = fminf(m2, fmaf(a2z, c.z, fmaf(a2y, c.y, fmaf(a2x, c.x, c.w))));
      m3 = fminf(m3, fmaf(a3z, c.z, fmaf(a3y, c.y, fmaf(a3x, c.x, c.w))));
    }
  }
  float T0 = thresh17(m0, lane) + 1e-3f;
  float T1 = thresh17(m1, lane) + 1e-3f;
  float T2 = thresh17(m2, lane) + 1e-3f;
  float T3 = thresh17(m3, lane) + 1e-3f;

  // Phase B: LDS-staged re-scan; rare branch; LDS atomic compaction
  for (int tb = 0; tb < 16; ++tb) {
    __syncthreads();
    ctile[t] = cb[tb * 512 + t];
    ctile[t + 256] = cb[tb * 512 + 256 + t];
    __syncthreads();
#pragma unroll
    for (int i = 0; i < 8; ++i) {
      float4 c = ctile[i * 64 + lane];
      float p0 = fmaf(a0z, c.z, fmaf(a0y, c.y, fmaf(a0x, c.x, c.w)));
      float p1 = fmaf(a1z, c.z, fmaf(a1y, c.y, fmaf(a1x, c.x, c.w)));
      float p2 = fmaf(a2z, c.z, fmaf(a2y, c.y, fmaf(a2x, c.x, c.w)));
      float p3 = fmaf(a3z, c.z, fmaf(a3y, c.y, fmaf(a3x, c.x, c.w)));
      bool h0 = p0 <= T0, h1 = p1 <= T1, h2 = p2 <= T2, h3 = p3 <= T3;
      if (h0 | h1 | h2 | h3) {
        int m = tb * 512 + i * 64 + lane;
        if (h0) { int p = atomicAdd(&scnt[wv][0], 1); if (p < 128) sii[wv][0][p] = m; }
        if (h1) { int p = atomicAdd(&scnt[wv][1], 1); if (p < 128) sii[wv][1][p] = m; }
        if (h2) { int p = atomicAdd(&scnt[wv][2], 1); if (p < 128) sii[wv][2][p] = m; }
        if (h3) { int p = atomicAdd(&scnt[wv][3], 1); if (p < 128) sii[wv][3][p] = m; }
      }
    }
  }
  __syncthreads();

  // Phase C: per query, exact f64 on survivors; (d64, idx)-lex bitonic select of 16
#pragma unroll 1
  for (int j = 0; j < 4; ++j) {
    int q = q0 + j;
    int n = q & (N_ - 1);
    int cnt = scnt[wv][j] < 128 ? scnt[wv][j] : 128;
    double4 me64 = cb64[n];
    double d1 = 1e300; int ix1 = 0x7FFFFFFF;
    if (lane < cnt) {
      int m = sii[wv][j][lane];
      if (m != n) {
        double4 c = cb64[m];
        double dot = (me64.x * c.x + me64.y * c.y) + me64.z * c.z;
        d1 = (me64.w + c.w) - 2.0 * dot;
        ix1 = m;
      }
    }
    bsort64d(d1, ix1, lane);
    if (cnt > 64) {
      double d2 = 1e300; int ix2 = 0x7FFFFFFF;
      if (lane + 64 < cnt) {
        int m = sii[wv][j][lane + 64];
        if (m != n) {
          double4 c = cb64[m];
          double dot = (me64.x * c.x + me64.y * c.y) + me64.z * c.z;
          d2 = (me64.w + c.w) - 2.0 * dot;
          ix2 = m;
        }
      }
      bsort64d(d2, ix2, lane);
      int src = (lane - 16) & 63;
      double dB = __shfl(d2, src, 64);
      int iB = __shfl(ix2, src, 64);
      double nd = (lane < 16) ? d1 : ((lane < 32) ? dB : 1e300);
      int nix = (lane < 16) ? ix1 : ((lane < 32) ? iB : 0x7FFFFFFF);
      bsort64d(nd, nix, lane);
      d1 = nd; ix1 = nix;
    }
    if (lane < 16) idxout[(size_t)q * 16 + lane] = ix1;
  }
}

// ---------------- MFMA bf16 GEMM (plain) ----------------
// C/D layout: col=lane&15, row=(lane>>4)*4+reg (guide m89/m91). OUT = bf16 or f32.
template <typename OUT>
__global__ __launch_bounds__(256) void gemm_mfma(const __hip_bfloat16* __restrict__ X, int ldx,
                                                 const __hip_bfloat16* __restrict__ W, int ldw,
                                                 OUT* __restrict__ Cc, int ldc, int Ktot) {
  __shared__ short As[64 * 40];          // 64 rows x 32 k, pad to 40
  int b = blockIdx.z;
  int n0 = blockIdx.x * 64, o0 = blockIdx.y * 64;
  int t = threadIdx.x;
  int lane = t & 63, wv = t >> 6;
  int nh = (wv & 1) * 32, oh = (wv >> 1) * 32;
  const __hip_bfloat16* Xb = X + (size_t)(b * N_ + n0) * ldx;
  f32x4 acc00 = {0.f, 0.f, 0.f, 0.f}, acc01 = acc00, acc10 = acc00, acc11 = acc00;
  int sr = t >> 2;            // 0..63 staging row
  int sc = (t & 3) * 8;       // 0,8,16,24
  int arow = lane & 15;
  int kq = (lane >> 4) * 8;
  for (int kt = 0; kt < Ktot; kt += 32) {
    short8 av = *(const short8*)&Xb[(size_t)sr * ldx + kt + sc];
    *(short8*)&As[sr * 40 + sc] = av;
    __syncthreads();
    short8 a0 = *(const short8*)&As[(nh + arow) * 40 + kq];
    short8 a1 = *(const short8*)&As[(nh + 16 + arow) * 40 + kq];
    const __hip_bfloat16* Wp = W + (size_t)(o0 + oh + arow) * ldw + kt + kq;
    short8 b0 = *(const short8*)&Wp[0];
    short8 b1 = *(const short8*)&Wp[16 * (size_t)ldw];
    acc00 = __builtin_amdgcn_mfma_f32_16x16x32_bf16(a0, b0, acc00, 0, 0, 0);
    acc01 = __builtin_amdgcn_mfma_f32_16x16x32_bf16(a0, b1, acc01, 0, 0, 0);
    acc10 = __builtin_amdgcn_mfma_f32_16x16x32_bf16(a1, b0, acc10, 0, 0, 0);
    acc11 = __builtin_amdgcn_mfma_f32_16x16x32_bf16(a1, b1, acc11, 0, 0, 0);
    __syncthreads();
  }
  int crow = (lane >> 4) * 4;
  int ccol = lane & 15;
#pragma unroll
  for (int r = 0; r < 4; ++r) {
    size_t row0 = (size_t)(b * N_ + n0 + nh + crow + r) * ldc + o0 + oh;
    size_t row1 = (size_t)(b * N_ + n0 + nh + 16 + crow + r) * ldc + o0 + oh;
    if constexpr (sizeof(OUT) == 4) {
      Cc[row0 + ccol]      = acc00[r];
      Cc[row0 + 16 + ccol] = acc01[r];
      Cc[row1 + ccol]      = acc10[r];
      Cc[row1 + 16 + ccol] = acc11[r];
    } else {
      Cc[row0 + ccol]      = ftob(acc00[r]);
      Cc[row0 + 16 + ccol] = ftob(acc01[r]);
      Cc[row1 + ccol]      = ftob(acc10[r]);
      Cc[row1 + 16 + ccol] = ftob(acc11[r]);
    }
  }
}

// ---------------- edge gather + max/sum/sumsq: bf16 PQ, 2 channels/thread, 64-query blocks ----------------
template <int CO>
__global__ __launch_bounds__(256) void edge_kernel(const __hip_bfloat16* __restrict__ PQ,
                                                   const int* __restrict__ idx,
                                                   __hip_bfloat16* __restrict__ Mout,  // ld 512
                                                   float* __restrict__ acc) {
  constexpr int CP = CO / 2;         // channel pairs
  constexpr int NG = 256 / CP;       // query groups (CO=128 -> 4, CO=256 -> 2)
  __shared__ float r1a[256], r1b[256], r2a[256], r2b[256];
  int b = blockIdx.y;
  int n0 = blockIdx.x * 64;
  int t = threadIdx.x;
  int oc = t & (CP - 1);
  int o2 = oc * 2;
  int qg = t / CP;
  float s1a = 0.f, s1b = 0.f, s2a = 0.f, s2b = 0.f;
  const __hip_bfloat16* PQb = PQ + (size_t)b * N_ * (2 * CO);
  for (int qq = qg; qq < 64; qq += NG) {
    int n = n0 + qq;
    const int4* ip = (const int4*)&idx[(size_t)(b * N_ + n) * 16];
    int4 i0 = ip[0], i1 = ip[1], i2 = ip[2], i3 = ip[3];
    unsigned pu = *(const unsigned*)&PQb[(size_t)n * (2 * CO) + o2];
    float pa = bf2f((unsigned short)(pu & 0xFFFF));
    float pb = bf2f((unsigned short)(pu >> 16));
    float hma = -INF_, hmb = -INF_;
#define EDGE_STEP(mm)                                                         \
    { int mc = (mm) & (N_ - 1);                                               \
      unsigned vu = *(const unsigned*)&PQb[(size_t)mc * (2 * CO) + CO + o2];  \
      float ha = pa + bf2f((unsigned short)(vu & 0xFFFF));                    \
      float hb = pb + bf2f((unsigned short)(vu >> 16));                       \
      hma = fmaxf(hma, ha); s1a += ha; s2a = fmaf(ha, ha, s2a);               \
      hmb = fmaxf(hmb, hb); s1b += hb; s2b = fmaf(hb, hb, s2b); }
    EDGE_STEP(i0.x) EDGE_STEP(i0.y) EDGE_STEP(i0.z) EDGE_STEP(i0.w)
    EDGE_STEP(i1.x) EDGE_STEP(i1.y) EDGE_STEP(i1.z) EDGE_STEP(i1.w)
    EDGE_STEP(i2.x) EDGE_STEP(i2.y) EDGE_STEP(i2.z) EDGE_STEP(i2.w)
    EDGE_STEP(i3.x) EDGE_STEP(i3.y) EDGE_STEP(i3.z) EDGE_STEP(i3.w)
#undef EDGE_STEP
    __hip_bfloat162 hh;
    hh.x = ftob(hma); hh.y = ftob(hmb);
    *(__hip_bfloat162*)&Mout[(size_t)(b * N_ + n) * 512 + o2] = hh;
  }
  r1a[t] = s1a; r1b[t] = s1b; r2a[t] = s2a; r2b[t] = s2b;
  __syncthreads();
  if (t < CP) {
#pragma unroll
    for (int g = 1; g < NG; ++g) {
      s1a += r1a[t + g * CP]; s1b += r1b[t + g * CP];
      s2a += r2a[t + g * CP]; s2b += r2b[t + g * CP];
    }
    atomicAdd(&acc[(b * CO + o2) * 2 + 0], s1a);
    atomicAdd(&acc[(b * CO + o2) * 2 + 1], s2a);
    atomicAdd(&acc[(b * CO + o2 + 1) * 2 + 0], s1b);
    atomicAdd(&acc[(b * CO + o2 + 1) * 2 + 1], s2b);
  }
}

// ---------------- in-place instance-norm + leaky on bf16 (after max-over-k) ----------------
template <int CO>
__global__ void norm_kernel(__hip_bfloat16* __restrict__ M, const float* __restrict__ acc) {
  int tid = blockIdx.x * 256 + threadIdx.x;  // over B*N*CO
  int o = tid & (CO - 1);
  int bn = tid / CO;
  int b = bn >> 13;
  float s1 = acc[(b * CO + o) * 2], s2 = acc[(b * CO + o) * 2 + 1];
  const float inv = 1.f / (float)NK_;
  float mean = s1 * inv;
  float var = fmaf(s2, inv, -mean * mean);
  float rs = rsqrtf(var + EPS_);
  float v = __bfloat162float(M[(size_t)bn * 512 + o]);
  float y = (v - mean) * rs;
  M[(size_t)bn * 512 + o] = ftob(y > 0.f ? y : SLOPE_ * y);
}

// ---------------- column sums for final inorm (R9-proven grid: 64 blocks total) ----------------
__global__ __launch_bounds__(256) void colred_kernel(const float* __restrict__ H,
                                                     float* __restrict__ acc3) {
  __shared__ float r1[256], r2[256];
  int b = blockIdx.y;
  int n0 = blockIdx.x * 256;
  int t = threadIdx.x;
  int o = t & 127, half = t >> 7;
  float s1 = 0.f, s2 = 0.f;
  for (int i = 0; i < 128; ++i) {
    int n = n0 + half * 128 + i;
    float v = H[(size_t)(b * N_ + n) * 128 + o];
    s1 += v; s2 = fmaf(v, v, s2);
  }
  r1[t] = s1; r2[t] = s2;
  __syncthreads();
  if (t < 128) {
    s1 = r1[t] + r1[t + 128];
    s2 = r2[t] + r2[t + 128];
    atomicAdd(&acc3[(b * 128 + o) * 2 + 0], s1);
    atomicAdd(&acc3[(b * 128 + o) * 2 + 1], s2);
  }
}

// ---------------- final: norm + leaky + transpose to (B,128,N) f32 (R9-proven grid) ----------------
__global__ __launch_bounds__(256) void final_kernel(const float* __restrict__ H,
                                                    const float* __restrict__ acc3,
                                                    float* __restrict__ out) {
  __shared__ float tile[64 * 132];
  int b = blockIdx.y, n0 = blockIdx.x * 64;
  int t = threadIdx.x;
  int r = t >> 5;           // 0..7
  int c4 = (t & 31) * 4;    // 0..124
#pragma unroll
  for (int i = 0; i < 8; ++i) {
    int row = r + i * 8;
    *(float4*)&tile[row * 132 + c4] = *(const float4*)&H[(size_t)(b * N_ + n0 + row) * 128 + c4];
  }
  __syncthreads();
  int o = t >> 1;
  int nh = (t & 1) * 32;
  float s1 = acc3[(b * 128 + o) * 2], s2 = acc3[(b * 128 + o) * 2 + 1];
  const float inv = 1.f / (float)N_;
  float mean = s1 * inv;
  float var = fmaf(s2, inv, -mean * mean);
  float rs = rsqrtf(var + EPS_);
#pragma unroll
  for (int i = 0; i < 32; ++i) {
    int nl = nh + i;
    float v = tile[nl * 132 + o];
    float y = (v - mean) * rs;
    y = y > 0.f ? y : SLOPE_ * y;
    out[(size_t)(b * 128 + o) * N_ + n0 + nl] = y;
  }
}

extern "C" void kernel_launch(void* const* d_in, const int* in_sizes, int n_in,
                              void* d_out, int out_size, void* d_ws, size_t ws_size,
                              hipStream_t stream) {
  const float* coords = (const float*)d_in[0];
  const float* feats = (const float*)d_in[1];
  const float* W1 = (const float*)d_in[2];
  const float* W2 = (const float*)d_in[3];
  const float* W3 = (const float*)d_in[4];
  char* ws = (char*)d_ws;
  int* idx = (int*)(ws + OFF_IDX);
  float4* cpk = (float4*)(ws + OFF_CPK);
  double4* cpk64 = (double4*)(ws + OFF_CPK64);
  float* acc = (float*)(ws + OFF_ACC);  // acc1 @ +0, acc2 @ +512, acc3 @ +1536 (floats)
  __hip_bfloat16* wc1 = (__hip_bfloat16*)(ws + OFF_WC1);
  __hip_bfloat16* wc2 = (__hip_bfloat16*)(ws + OFF_WC2);
  __hip_bfloat16* wb3 = (__hip_bfloat16*)(ws + OFF_WB3);
  __hip_bfloat16* x3t = (__hip_bfloat16*)(ws + OFF_X3T);
  __hip_bfloat16* pqb = (__hip_bfloat16*)(ws + OFF_PQ);  // pq1/pq2 bf16
  float* ht = (float*)(ws + OFF_PQ);                     // ht f32 aliases (pq2 dead by then)

  prep_kernel<<<712, 256, 0, stream>>>(coords, W1, W2, W3, wc1, wc2, wb3, cpk, cpk64, acc);
  transpose_kernel<<<dim3(128, 2, 2), 256, 0, stream>>>(feats, x3t);
  knn_kernel<<<1024, 256, 0, stream>>>(cpk, cpk64, idx);
  // block 1: pqb[b][n][0:128]=P1, [128:256]=Q1
  gemm_mfma<__hip_bfloat16><<<dim3(128, 4, 2), 256, 0, stream>>>(x3t, 512, wc1, 128, pqb, 256, 128);
  edge_kernel<128><<<dim3(128, 2), 256, 0, stream>>>(pqb, idx, x3t + 128, acc + 0);
  norm_kernel<128><<<(B_ * N_ * 128) / 256, 256, 0, stream>>>(x3t + 128, acc + 0);
  // block 2: pqb[b][n][0:256]=P2, [256:512]=Q2
  gemm_mfma<__hip_bfloat16><<<dim3(128, 8, 2), 256, 0, stream>>>(x3t + 128, 512, wc2, 128, pqb, 512, 128);
  edge_kernel<256><<<dim3(128, 2), 256, 0, stream>>>(pqb, idx, x3t + 256, acc + 512);
  norm_kernel<256><<<(B_ * N_ * 256) / 256, 256, 0, stream>>>(x3t + 256, acc + 512);
  // final projection + inorm; ht aliases pq region (pq2 dead)
  gemm_mfma<float><<<dim3(128, 2, 2), 256, 0, stream>>>(x3t, 512, wb3, 512, ht, 128, 512);
  colred_kernel<<<dim3(32, 2), 256, 0, stream>>>(ht, acc + 1536);
  final_kernel<<<dim3(128, 2), 256, 0, stream>>>(ht, acc + 1536, (float*)d_out);
}